// Round 5
// baseline (195.060 us; speedup 1.0000x reference)
//
#include <hip/hip_runtime.h>
#include <stdint.h>
#include <math.h>

// Problem constants
#define NB_B 8
#define NB_S 512
#define NB_D 1024
#define NB_H 16
#define NB_HD 64
#define NP 196            // image patches: bidirectional prefix block
#define MTOT 4096         // B*S

// Workspace layout (offsets in bf16/short elements). Total 25165824 shorts = 48 MB.
#define OFF_XB 0
#define OFF_WQ 4194304
#define OFF_WK 5242880
#define OFF_WV 6291456
#define OFF_WO 7340032
#define OFF_Q  8388608
#define OFF_K  12582912
#define OFF_VT 16777216
#define OFF_CT 20971520

typedef __attribute__((ext_vector_type(8))) short bf16x8;
typedef __attribute__((ext_vector_type(4))) float f32x4;
typedef __attribute__((ext_vector_type(4))) short s16x4;

__device__ __forceinline__ short f2bf(float f) {
  union { float f; uint32_t u; } c; c.f = f;
  uint32_t r = (c.u + 0x7fffu + ((c.u >> 16) & 1u)) >> 16;   // RNE
  return (short)r;
}

// pack two fp32 -> one dword of two bf16 (round-half-up; inputs are positive
// softmax weights or zeros, so the cheap +0x8000 rounding is safe)
__device__ __forceinline__ uint32_t pack2bf(float lo, float hi) {
  uint32_t ulo = __float_as_uint(lo) + 0x8000u;
  uint32_t uhi = __float_as_uint(hi) + 0x8000u;
  return __builtin_amdgcn_perm(uhi, ulo, 0x07060302u);  // [bf16(hi)|bf16(lo)]
}

__device__ __forceinline__ void async16(void* lds, const void* g) {
  // global -> LDS direct copy, 16B per lane; LDS dest = uniform base + lane*16
  __builtin_amdgcn_global_load_lds(
      (const __attribute__((address_space(1))) void*)g,
      (__attribute__((address_space(3))) void*)lds, 16, 0, 0);
}

// ---------------------------------------------------------------------------
// fp32 -> bf16 conversion for x and the 4 weight matrices (one fused launch).
// w_q gets the 1/sqrt(hd)=0.125 softmax scale folded in (exact pow2 in bf16).
// ---------------------------------------------------------------------------
__global__ __launch_bounds__(256) void cvt5(const float* __restrict__ x,
                                            const float* __restrict__ wq,
                                            const float* __restrict__ wk,
                                            const float* __restrict__ wv,
                                            const float* __restrict__ wo,
                                            short* __restrict__ ws) {
  int b = blockIdx.x, t = threadIdx.x;
  const float* src; short* dst; float scale;
  if (b < 4096) { src = x + b * 1024; dst = ws + OFF_XB + b * 1024; scale = 1.0f; }
  else {
    int wb = b - 4096, wi = wb >> 10, r = wb & 1023;
    switch (wi) {
      case 0:  src = wq + r * 1024; dst = ws + OFF_WQ + r * 1024; scale = 0.125f; break;
      case 1:  src = wk + r * 1024; dst = ws + OFF_WK + r * 1024; scale = 1.0f;   break;
      case 2:  src = wv + r * 1024; dst = ws + OFF_WV + r * 1024; scale = 1.0f;   break;
      default: src = wo + r * 1024; dst = ws + OFF_WO + r * 1024; scale = 1.0f;   break;
    }
  }
  int i = t << 2;
  float4 v = *(const float4*)(src + i);
  s16x4 o;
  o[0] = f2bf(v.x * scale); o[1] = f2bf(v.y * scale);
  o[2] = f2bf(v.z * scale); o[3] = f2bf(v.w * scale);
  *(s16x4*)(dst + i) = o;
}

// ---------------------------------------------------------------------------
// Fused QKV projection v2: ONE dispatch computes Q, K, V.
//   R4 post-mortem: separate Q/K/V grids staged x three times and had only
//   16 MFMA per barrier pair (MfmaUtil 17% vs m97's 37%); 768 blocks over
//   512 co-resident slots left a ragged tail. Fix: tile 64m x 128n, all
//   three outputs per block. Per BK=32 step: 28 x 1KB frag-swizzled chunks
//   (A 4 + 3 weights x 8), 7 async16 per wave; per wave: 24 MFMA, 10
//   ds_read_b128, 2 barriers. Grid 512 = exactly 2 blocks/CU, no tail.
//   bx=mt*8+nt => XCD j sees only n-slice j (weights L2-resident per XCD).
//   Wave owns n-cols [wvi*32, wvi*32+32) x all 64 m rows.
//   acc = 3x4x2 f32x4 = 96 VGPR.
// ---------------------------------------------------------------------------
__global__ __launch_bounds__(256, 2) void gemm_qkv(short* __restrict__ ws) {
  __shared__ __align__(16) short Ls[14336];   // 28 chunks x 512 shorts = 28KB
  int bx = blockIdx.x;              // 0..511
  int mt = bx >> 3, nt = bx & 7;
  int m0 = mt << 6, n0 = nt << 7;
  const short* A = ws + OFF_XB;
  int t = threadIdx.x, lane = t & 63, wvi = t >> 6;
  int c = lane & 15, quad = lane >> 4;
  f32x4 acc[3][4][2] = {};

  for (int kk = 0; kk < 1024; kk += 32) {
    // --- stage 28 chunks, 7 per wave (wave-uniform chunk ids) ---
#pragma unroll
    for (int i = 0; i < 7; ++i) {
      int ch = wvi * 7 + i;
      const short* src;
      if (ch < 4) {
        src = A + (m0 + ch * 16 + c) * 1024 + kk + (quad << 3);
      } else {
        int cw = (ch - 4) >> 3, cb = (ch - 4) & 7;  // weight, 16-row group
        src = ws + OFF_WQ + cw * 1048576 + (n0 + cb * 16 + c) * 1024 + kk + (quad << 3);
      }
      async16(&Ls[ch << 9], src);
    }
    __syncthreads();                // drains vmcnt for global_load_lds

    bf16x8 af[4];
#pragma unroll
    for (int mb = 0; mb < 4; ++mb) af[mb] = *(const bf16x8*)&Ls[(mb << 9) + lane * 8];
#pragma unroll
    for (int w = 0; w < 3; ++w) {
#pragma unroll
      for (int nb = 0; nb < 2; ++nb) {
        bf16x8 bf = *(const bf16x8*)&Ls[((4 + w * 8 + wvi * 2 + nb) << 9) + lane * 8];
#pragma unroll
        for (int mb = 0; mb < 4; ++mb)
          acc[w][mb][nb] = __builtin_amdgcn_mfma_f32_16x16x32_bf16(af[mb], bf, acc[w][mb][nb], 0, 0, 0);
      }
    }
    __syncthreads();                // protect LDS before next stage
  }

  // --- epilogue: Q,K -> [B,H,S,hd]; V -> transposed [B,H,hd,S] ---
#pragma unroll
  for (int w = 0; w < 3; ++w) {
#pragma unroll
    for (int nb = 0; nb < 2; ++nb) {
      int n = n0 + wvi * 32 + nb * 16 + c;      // output feature
      int h = n >> 6, d = n & 63;
#pragma unroll
      for (int mb = 0; mb < 4; ++mb) {
        int m = m0 + mb * 16 + (quad << 2);     // first of 4 rows (reg dim)
        int bb = m >> 9, s = m & 511;
        if (w < 2) {
          short* outp = ws + OFF_Q + w * 4194304;
#pragma unroll
          for (int r = 0; r < 4; ++r)
            outp[((bb * 16 + h) * 512 + s + r) * 64 + d] = f2bf(acc[w][mb][nb][r]);
        } else {
          s16x4 o;
#pragma unroll
          for (int r = 0; r < 4; ++r) o[r] = f2bf(acc[w][mb][nb][r]);
          *(s16x4*)&ws[OFF_VT + ((bb * 16 + h) * 64 + d) * 512 + s] = o;
        }
      }
    }
  }
}

// ---------------------------------------------------------------------------
// Attention v4 (block-cooperative flash, LDS-staged K/V) — unchanged from R4.
// ---------------------------------------------------------------------------
__global__ __launch_bounds__(256, 2) void attn(short* __restrict__ ws) {
  __shared__ __align__(16) short Kb[4096];   // 64 keys x 64 d, 8 frag chunks
  __shared__ __align__(16) short Vb[4096];   // 64 d x 64 keys, 8 frag chunks
  int bi = blockIdx.x;              // 0..511
  int bh = bi >> 2, qcr = bi & 3;
  int qc = (qcr + bh + 2 * (bh >> 6)) & 3;   // rotate so CU pairs mix light/heavy
  int t = threadIdx.x, lane = t & 63, wvi = t >> 6;
  int c = lane & 15, quad = lane >> 4;
  const short* Qh  = ws + OFF_Q  + bh * (512 * 64);
  const short* Kh  = ws + OFF_K  + bh * (512 * 64);
  const short* Vth = ws + OFF_VT + bh * (64 * 512);
  short* ctx = ws + OFF_CT;
  int b = bh >> 4, h = bh & 15;

  int qt0 = qc * 128 + wvi * 32;    // two 16-row subtiles per wave
  int qt1 = qt0 + 16;
  int kn0 = (qt0 + 16 > NP) ? (qt0 + 16) : NP;
  int kn1 = (qt1 + 16 > NP) ? (qt1 + 16) : NP;
  int knb = (qc * 128 + 128 > NP) ? (qc * 128 + 128) : NP;
  int NCH = (knb + 63) >> 6;        // 64-key chunks staged by the block

  // Q^T B-frags for both subtiles: [n=q=lane&15][k=d=quad*8+j] (+32 frag 1)
  bf16x8 q00 = *(const bf16x8*)(Qh + (qt0 + c) * 64 + (quad << 3));
  bf16x8 q01 = *(const bf16x8*)(Qh + (qt0 + c) * 64 + 32 + (quad << 3));
  bf16x8 q10 = *(const bf16x8*)(Qh + (qt1 + c) * 64 + (quad << 3));
  bf16x8 q11 = *(const bf16x8*)(Qh + (qt1 + c) * 64 + 32 + (quad << 3));

  f32x4 acc0[4] = {}, acc1[4] = {}; // ctx^T accumulators per subtile
  float l0 = 0.0f, l1 = 0.0f;       // in-lane softmax denominators
  int L0 = c + ((quad & 1) << 5);   // transpose source lane
  bool hilo = quad >= 2;

  for (int ch = 0; ch < NCH; ++ch) {
    int k0 = ch << 6;
    // --- stage K[k0..k0+63][0..63] and V^T[0..63][k0..k0+63], frag-swizzled.
    {
      const short* gk = Kh + (k0 + wvi * 16 + c) * 64 + (quad << 3);
      async16(&Kb[(wvi * 2 + 0) << 9], gk);
      async16(&Kb[(wvi * 2 + 1) << 9], gk + 32);
      const short* gv = Vth + (wvi * 16 + c) * 512 + k0 + (quad << 3);
      async16(&Vb[(wvi * 2 + 0) << 9], gv);
      async16(&Vb[(wvi * 2 + 1) << 9], gv + 32);
    }
    __syncthreads();                // drains vmcnt for global_load_lds

    // K A-frags [m=key16][k=d] and V^T A-frags [m=d16][k=key32+..]
    bf16x8 ak[4][2], av[4][2];
#pragma unroll
    for (int mb = 0; mb < 4; ++mb)
#pragma unroll
      for (int f = 0; f < 2; ++f) {
        ak[mb][f] = *(const bf16x8*)&Kb[((mb * 2 + f) << 9) + lane * 8];
        av[mb][f] = *(const bf16x8*)&Vb[((mb * 2 + f) << 9) + lane * 8];
      }

#pragma unroll
    for (int s = 0; s < 2; ++s) {
      int qt = s ? qt1 : qt0;
      int kn = s ? kn1 : kn0;
      if (k0 >= kn) continue;       // subtile finished (other subtile may not be)
      bf16x8 bq0 = s ? q10 : q00;
      bf16x8 bq1 = s ? q11 : q01;
      f32x4* acc = s ? acc1 : acc0;

      // --- S^T = K . Q^T : 4 m-blocks of 16 keys ---
      float p[4][4];
#pragma unroll
      for (int mb = 0; mb < 4; ++mb) {
        f32x4 st = {};
        st = __builtin_amdgcn_mfma_f32_16x16x32_bf16(ak[mb][0], bq0, st, 0, 0, 0);
        st = __builtin_amdgcn_mfma_f32_16x16x32_bf16(ak[mb][1], bq1, st, 0, 0, 0);
#pragma unroll
        for (int r = 0; r < 4; ++r) p[mb][r] = __expf(st[r]);
      }

      // --- prefix/causal mask (only chunks that can contain invalid keys) ---
      if ((k0 + 64 > NP) && (k0 + 64 > qt + 1)) {
        int row = qt + c;
#pragma unroll
        for (int mb = 0; mb < 4; ++mb)
#pragma unroll
          for (int r = 0; r < 4; ++r) {
            int key = k0 + mb * 16 + (quad << 2) + r;
            bool v = (row < NP) ? (key < NP) : (key <= row);
            p[mb][r] = v ? p[mb][r] : 0.0f;
          }
      }
      float ls = 0.0f;
#pragma unroll
      for (int mb = 0; mb < 4; ++mb)
#pragma unroll
        for (int r = 0; r < 4; ++r) ls += p[mb][r];
      if (s) l1 += ls; else l0 += ls;

      // --- per 32-key half: transpose to B-frag (R3-verified), then PV ---
#pragma unroll
      for (int hh = 0; hh < 2; ++hh) {
        float* pa = p[2 * hh];      // keys k0+32hh+{4quad'+r}
        float* pb = p[2 * hh + 1];  // keys k0+32hh+16+{4quad'+r}
        uint32_t e0 = pack2bf(pa[0], pa[1]);
        uint32_t e1 = pack2bf(pa[2], pa[3]);
        uint32_t e2 = pack2bf(pb[0], pb[1]);
        uint32_t e3 = pack2bf(pb[2], pb[3]);
        uint32_t a0 = (uint32_t)__shfl((int)e0, L0);
        uint32_t b0 = (uint32_t)__shfl((int)e1, L0);
        uint32_t a1 = (uint32_t)__shfl((int)e0, L0 + 16);
        uint32_t b1 = (uint32_t)__shfl((int)e1, L0 + 16);
        uint32_t c0 = (uint32_t)__shfl((int)e2, L0);
        uint32_t d0 = (uint32_t)__shfl((int)e3, L0);
        uint32_t c1 = (uint32_t)__shfl((int)e2, L0 + 16);
        uint32_t d1 = (uint32_t)__shfl((int)e3, L0 + 16);
        union { uint32_t u[4]; bf16x8 v; } bp;
        bp.u[0] = hilo ? c0 : a0;
        bp.u[1] = hilo ? d0 : b0;
        bp.u[2] = hilo ? c1 : a1;
        bp.u[3] = hilo ? d1 : b1;
#pragma unroll
        for (int db = 0; db < 4; ++db)
          acc[db] = __builtin_amdgcn_mfma_f32_16x16x32_bf16(av[db][hh], bp.v, acc[db], 0, 0, 0);
      }
    }
    __syncthreads();                // protect LDS before next stage
  }

  // --- finalize both subtiles: quad-reduce l, normalize, 8B stores ---
#pragma unroll
  for (int s = 0; s < 2; ++s) {
    float l = s ? l1 : l0;
    f32x4* acc = s ? acc1 : acc0;
    int qt = s ? qt1 : qt0;
    l += __shfl_xor(l, 16);
    l += __shfl_xor(l, 32);
    float inv = 1.0f / l;
    size_t rowbase = ((size_t)(b * 512 + qt + c)) * 1024 + h * 64 + (quad << 2);
#pragma unroll
    for (int db = 0; db < 4; ++db) {
      s16x4 o;
#pragma unroll
      for (int r = 0; r < 4; ++r) o[r] = f2bf(acc[db][r] * inv);
      *(s16x4*)&ctx[rowbase + db * 16] = o;
    }
  }
}

// ---------------------------------------------------------------------------
// Output projection: out = ctx @ w_o^T + b_o  (fp32 out). Same gemm_bt body.
// ---------------------------------------------------------------------------
__global__ __launch_bounds__(256, 2) void gemm_out(const short* __restrict__ ws,
                                                   const float* __restrict__ bias,
                                                   float* __restrict__ out) {
  __shared__ __align__(16) short As[4096];
  __shared__ __align__(16) short Bs[4096];
  int tile = blockIdx.x;            // 0..255
  int mt = tile >> 3, nt = tile & 7;
  int m0 = mt << 7, n0 = nt << 7;
  const short* A  = ws + OFF_CT;
  const short* Bw = ws + OFF_WO;
  int t = threadIdx.x, lane = t & 63, wvi = t >> 6;
  int c = lane & 15, quad = lane >> 4;
  int wm = wvi >> 1, wn = wvi & 1;
  f32x4 acc[4][4] = {};

  for (int kk = 0; kk < 1024; kk += 32) {
#pragma unroll
    for (int i = 0; i < 2; ++i) {
      int ch = wvi * 2 + i;
      async16(&As[ch << 9], A  + (m0 + ch * 16 + c) * 1024 + kk + (quad << 3));
      async16(&Bs[ch << 9], Bw + (n0 + ch * 16 + c) * 1024 + kk + (quad << 3));
    }
    __syncthreads();
    bf16x8 af[4], bfr[4];
#pragma unroll
    for (int i = 0; i < 4; ++i) af[i]  = *(const bf16x8*)&As[((wm * 4 + i) * 64 + lane) * 8];
#pragma unroll
    for (int j = 0; j < 4; ++j) bfr[j] = *(const bf16x8*)&Bs[((wn * 4 + j) * 64 + lane) * 8];
#pragma unroll
    for (int i = 0; i < 4; ++i)
#pragma unroll
      for (int j = 0; j < 4; ++j)
        acc[i][j] = __builtin_amdgcn_mfma_f32_16x16x32_bf16(af[i], bfr[j], acc[i][j], 0, 0, 0);
    __syncthreads();
  }

#pragma unroll
  for (int j = 0; j < 4; ++j) {
    int n = n0 + wn * 64 + j * 16 + c;
    float bj = bias[n];
#pragma unroll
    for (int i = 0; i < 4; ++i) {
      int mq = m0 + wm * 64 + i * 16 + quad * 4;
#pragma unroll
      for (int r = 0; r < 4; ++r)
        out[(size_t)(mq + r) * 1024 + n] = acc[i][j][r] + bj;
    }
  }
}

extern "C" void kernel_launch(void* const* d_in, const int* in_sizes, int n_in,
                              void* d_out, int out_size, void* d_ws, size_t ws_size,
                              hipStream_t stream) {
  (void)in_sizes; (void)n_in; (void)out_size; (void)ws_size;  // needs 48 MB of d_ws
  const float* x  = (const float*)d_in[0];
  const float* wq = (const float*)d_in[1];
  const float* wk = (const float*)d_in[2];
  const float* wv = (const float*)d_in[3];
  const float* wo = (const float*)d_in[4];
  const float* bo = (const float*)d_in[5];
  short* ws = (short*)d_ws;
  float* out = (float*)d_out;

  cvt5<<<8192, 256, 0, stream>>>(x, wq, wk, wv, wo, ws);
  gemm_qkv<<<512, 256, 0, stream>>>(ws);
  attn<<<512, 256, 0, stream>>>(ws);
  gemm_out<<<256, 256, 0, stream>>>(ws, bo, out);
}

// Round 6
// 193.864 us; speedup vs baseline: 1.0062x; 1.0062x over previous
//
#include <hip/hip_runtime.h>
#include <stdint.h>
#include <math.h>

// Problem constants
#define NB_B 8
#define NB_S 512
#define NB_D 1024
#define NB_H 16
#define NB_HD 64
#define NP 196            // image patches: bidirectional prefix block
#define MTOT 4096         // B*S

// Workspace layout (offsets in bf16/short elements). Total 25165824 shorts = 48 MB.
#define OFF_XB 0
#define OFF_WQ 4194304
#define OFF_WK 5242880
#define OFF_WV 6291456
#define OFF_WO 7340032
#define OFF_Q  8388608
#define OFF_K  12582912
#define OFF_VT 16777216
#define OFF_CT 20971520

typedef __attribute__((ext_vector_type(8))) short bf16x8;
typedef __attribute__((ext_vector_type(4))) float f32x4;
typedef __attribute__((ext_vector_type(4))) short s16x4;

__device__ __forceinline__ short f2bf(float f) {
  union { float f; uint32_t u; } c; c.f = f;
  uint32_t r = (c.u + 0x7fffu + ((c.u >> 16) & 1u)) >> 16;   // RNE
  return (short)r;
}

// pack two fp32 -> one dword of two bf16 (round-half-up; inputs are positive
// softmax weights or zeros, so the cheap +0x8000 rounding is safe)
__device__ __forceinline__ uint32_t pack2bf(float lo, float hi) {
  uint32_t ulo = __float_as_uint(lo) + 0x8000u;
  uint32_t uhi = __float_as_uint(hi) + 0x8000u;
  return __builtin_amdgcn_perm(uhi, ulo, 0x07060302u);  // [bf16(hi)|bf16(lo)]
}

__device__ __forceinline__ void async16(void* lds, const void* g) {
  // global -> LDS direct copy, 16B per lane; LDS dest = uniform base + lane*16
  __builtin_amdgcn_global_load_lds(
      (const __attribute__((address_space(1))) void*)g,
      (__attribute__((address_space(3))) void*)lds, 16, 0, 0);
}

// ---------------------------------------------------------------------------
// fp32 -> bf16 conversion for x and the 4 weight matrices (one fused launch).
// w_q gets the 1/sqrt(hd)=0.125 softmax scale folded in (exact pow2 in bf16).
// ---------------------------------------------------------------------------
__global__ __launch_bounds__(256) void cvt5(const float* __restrict__ x,
                                            const float* __restrict__ wq,
                                            const float* __restrict__ wk,
                                            const float* __restrict__ wv,
                                            const float* __restrict__ wo,
                                            short* __restrict__ ws) {
  int b = blockIdx.x, t = threadIdx.x;
  const float* src; short* dst; float scale;
  if (b < 4096) { src = x + b * 1024; dst = ws + OFF_XB + b * 1024; scale = 1.0f; }
  else {
    int wb = b - 4096, wi = wb >> 10, r = wb & 1023;
    switch (wi) {
      case 0:  src = wq + r * 1024; dst = ws + OFF_WQ + r * 1024; scale = 0.125f; break;
      case 1:  src = wk + r * 1024; dst = ws + OFF_WK + r * 1024; scale = 1.0f;   break;
      case 2:  src = wv + r * 1024; dst = ws + OFF_WV + r * 1024; scale = 1.0f;   break;
      default: src = wo + r * 1024; dst = ws + OFF_WO + r * 1024; scale = 1.0f;   break;
    }
  }
  int i = t << 2;
  float4 v = *(const float4*)(src + i);
  s16x4 o;
  o[0] = f2bf(v.x * scale); o[1] = f2bf(v.y * scale);
  o[2] = f2bf(v.z * scale); o[3] = f2bf(v.w * scale);
  *(s16x4*)(dst + i) = o;
}

// ---------------------------------------------------------------------------
// QKV projection v3 (R4 shape + BK=64):
//   R5 post-mortem: fused-wide-tile regressed because staged-bytes-per-MFMA
//   worsened (3.4 vs 4.0 MFMA/KB) while the per-barrier vmcnt(0) drain count
//   stayed 32. This version keeps R4's 3-in-1-dispatch 128x128 tiling
//   (768 blocks = 3/CU) and halves the drain count: BK=64 -> 16 iterations,
//   per wave-iter 32 MFMA : 16 ds_read_b128 : 8 async16. LDS 32KB -> 3
//   blocks/CU = 96KB fits. launch_bounds(256,3) caps VGPR at ~170 (est 160).
//   Epilogue unchanged (R4-verified): Q,K -> [B,H,S,hd]; V -> [B,H,hd,S].
// ---------------------------------------------------------------------------
__global__ __launch_bounds__(256, 3) void gemm_qkv(short* __restrict__ ws) {
  __shared__ __align__(16) short As[8192];   // 128 rows x 64 k, 16 chunks
  __shared__ __align__(16) short Bs[8192];
  int bx = blockIdx.x;              // 0..767
  int wsel = bx >> 8;               // 0=Q 1=K 2=V
  int tile = bx & 255;
  int mt = tile >> 3, nt = tile & 7;
  int m0 = mt << 7, n0 = nt << 7;
  const short* A  = ws + OFF_XB;
  const short* Bw = ws + (wsel == 0 ? OFF_WQ : (wsel == 1 ? OFF_WK : OFF_WV));
  int t = threadIdx.x, lane = t & 63, wvi = t >> 6;
  int c = lane & 15, quad = lane >> 4;
  int wm = wvi >> 1, wn = wvi & 1;
  f32x4 acc[4][4] = {};

  for (int kk = 0; kk < 1024; kk += 64) {
    // --- stage 32 chunks (16 A + 16 B), 8 per wave, frag-swizzled ---
    // chunk = mg*2+kh: rows [16*mg,16*mg+16), k [kk+32*kh, +32)
#pragma unroll
    for (int i = 0; i < 8; ++i) {
      int ch = wvi * 8 + i;
      if (ch < 16) {
        int mg = ch >> 1, kh = ch & 1;
        async16(&As[ch << 9], A + (m0 + mg * 16 + c) * 1024 + kk + kh * 32 + (quad << 3));
      } else {
        int cb = ch - 16, mg = cb >> 1, kh = cb & 1;
        async16(&Bs[cb << 9], Bw + (n0 + mg * 16 + c) * 1024 + kk + kh * 32 + (quad << 3));
      }
    }
    __syncthreads();                // drains vmcnt for global_load_lds

    bf16x8 af[4][2], bfr[4][2];
#pragma unroll
    for (int i = 0; i < 4; ++i)
#pragma unroll
      for (int kh = 0; kh < 2; ++kh) {
        af[i][kh]  = *(const bf16x8*)&As[((((wm * 4 + i) << 1) + kh) << 9) + lane * 8];
        bfr[i][kh] = *(const bf16x8*)&Bs[((((wn * 4 + i) << 1) + kh) << 9) + lane * 8];
      }
#pragma unroll
    for (int kh = 0; kh < 2; ++kh)
#pragma unroll
      for (int i = 0; i < 4; ++i)
#pragma unroll
        for (int j = 0; j < 4; ++j)
          acc[i][j] = __builtin_amdgcn_mfma_f32_16x16x32_bf16(af[i][kh], bfr[j][kh], acc[i][j], 0, 0, 0);
    __syncthreads();                // protect LDS before next stage
  }

  short* outp = ws + (wsel == 0 ? OFF_Q : (wsel == 1 ? OFF_K : OFF_VT));
#pragma unroll
  for (int i = 0; i < 4; ++i) {
#pragma unroll
    for (int j = 0; j < 4; ++j) {
      int n = n0 + wn * 64 + j * 16 + c;        // output feature
      int h = n >> 6, d = n & 63;
      int mq = m0 + wm * 64 + i * 16 + quad * 4; // first of the 4 rows (reg dim)
      int bb = mq >> 9, s = mq & 511;
      if (wsel < 2) {
        // [B,H,S,hd]
#pragma unroll
        for (int r = 0; r < 4; ++r)
          outp[((bb * 16 + h) * 512 + (s + r)) * 64 + d] = f2bf(acc[i][j][r]);
      } else {
        // V transposed: [B,H,hd,S]; the 4 regs are 4 consecutive s -> 8B store
        s16x4 o;
#pragma unroll
        for (int r = 0; r < 4; ++r) o[r] = f2bf(acc[i][j][r]);
        *(s16x4*)&outp[((bb * 16 + h) * 64 + d) * 512 + s] = o;
      }
    }
  }
}

// ---------------------------------------------------------------------------
// Attention v4 (block-cooperative flash, LDS-staged K/V) — unchanged from R4.
// ---------------------------------------------------------------------------
__global__ __launch_bounds__(256, 2) void attn(short* __restrict__ ws) {
  __shared__ __align__(16) short Kb[4096];   // 64 keys x 64 d, 8 frag chunks
  __shared__ __align__(16) short Vb[4096];   // 64 d x 64 keys, 8 frag chunks
  int bi = blockIdx.x;              // 0..511
  int bh = bi >> 2, qcr = bi & 3;
  int qc = (qcr + bh + 2 * (bh >> 6)) & 3;   // rotate so CU pairs mix light/heavy
  int t = threadIdx.x, lane = t & 63, wvi = t >> 6;
  int c = lane & 15, quad = lane >> 4;
  const short* Qh  = ws + OFF_Q  + bh * (512 * 64);
  const short* Kh  = ws + OFF_K  + bh * (512 * 64);
  const short* Vth = ws + OFF_VT + bh * (64 * 512);
  short* ctx = ws + OFF_CT;
  int b = bh >> 4, h = bh & 15;

  int qt0 = qc * 128 + wvi * 32;    // two 16-row subtiles per wave
  int qt1 = qt0 + 16;
  int kn0 = (qt0 + 16 > NP) ? (qt0 + 16) : NP;
  int kn1 = (qt1 + 16 > NP) ? (qt1 + 16) : NP;
  int knb = (qc * 128 + 128 > NP) ? (qc * 128 + 128) : NP;
  int NCH = (knb + 63) >> 6;        // 64-key chunks staged by the block

  // Q^T B-frags for both subtiles: [n=q=lane&15][k=d=quad*8+j] (+32 frag 1)
  bf16x8 q00 = *(const bf16x8*)(Qh + (qt0 + c) * 64 + (quad << 3));
  bf16x8 q01 = *(const bf16x8*)(Qh + (qt0 + c) * 64 + 32 + (quad << 3));
  bf16x8 q10 = *(const bf16x8*)(Qh + (qt1 + c) * 64 + (quad << 3));
  bf16x8 q11 = *(const bf16x8*)(Qh + (qt1 + c) * 64 + 32 + (quad << 3));

  f32x4 acc0[4] = {}, acc1[4] = {}; // ctx^T accumulators per subtile
  float l0 = 0.0f, l1 = 0.0f;       // in-lane softmax denominators
  int L0 = c + ((quad & 1) << 5);   // transpose source lane
  bool hilo = quad >= 2;

  for (int ch = 0; ch < NCH; ++ch) {
    int k0 = ch << 6;
    // --- stage K[k0..k0+63][0..63] and V^T[0..63][k0..k0+63], frag-swizzled.
    {
      const short* gk = Kh + (k0 + wvi * 16 + c) * 64 + (quad << 3);
      async16(&Kb[(wvi * 2 + 0) << 9], gk);
      async16(&Kb[(wvi * 2 + 1) << 9], gk + 32);
      const short* gv = Vth + (wvi * 16 + c) * 512 + k0 + (quad << 3);
      async16(&Vb[(wvi * 2 + 0) << 9], gv);
      async16(&Vb[(wvi * 2 + 1) << 9], gv + 32);
    }
    __syncthreads();                // drains vmcnt for global_load_lds

    // K A-frags [m=key16][k=d] and V^T A-frags [m=d16][k=key32+..]
    bf16x8 ak[4][2], av[4][2];
#pragma unroll
    for (int mb = 0; mb < 4; ++mb)
#pragma unroll
      for (int f = 0; f < 2; ++f) {
        ak[mb][f] = *(const bf16x8*)&Kb[((mb * 2 + f) << 9) + lane * 8];
        av[mb][f] = *(const bf16x8*)&Vb[((mb * 2 + f) << 9) + lane * 8];
      }

#pragma unroll
    for (int s = 0; s < 2; ++s) {
      int qt = s ? qt1 : qt0;
      int kn = s ? kn1 : kn0;
      if (k0 >= kn) continue;       // subtile finished (other subtile may not be)
      bf16x8 bq0 = s ? q10 : q00;
      bf16x8 bq1 = s ? q11 : q01;
      f32x4* acc = s ? acc1 : acc0;

      // --- S^T = K . Q^T : 4 m-blocks of 16 keys ---
      float p[4][4];
#pragma unroll
      for (int mb = 0; mb < 4; ++mb) {
        f32x4 st = {};
        st = __builtin_amdgcn_mfma_f32_16x16x32_bf16(ak[mb][0], bq0, st, 0, 0, 0);
        st = __builtin_amdgcn_mfma_f32_16x16x32_bf16(ak[mb][1], bq1, st, 0, 0, 0);
#pragma unroll
        for (int r = 0; r < 4; ++r) p[mb][r] = __expf(st[r]);
      }

      // --- prefix/causal mask (only chunks that can contain invalid keys) ---
      if ((k0 + 64 > NP) && (k0 + 64 > qt + 1)) {
        int row = qt + c;
#pragma unroll
        for (int mb = 0; mb < 4; ++mb)
#pragma unroll
          for (int r = 0; r < 4; ++r) {
            int key = k0 + mb * 16 + (quad << 2) + r;
            bool v = (row < NP) ? (key < NP) : (key <= row);
            p[mb][r] = v ? p[mb][r] : 0.0f;
          }
      }
      float ls = 0.0f;
#pragma unroll
      for (int mb = 0; mb < 4; ++mb)
#pragma unroll
        for (int r = 0; r < 4; ++r) ls += p[mb][r];
      if (s) l1 += ls; else l0 += ls;

      // --- per 32-key half: transpose to B-frag (R3-verified), then PV ---
#pragma unroll
      for (int hh = 0; hh < 2; ++hh) {
        float* pa = p[2 * hh];      // keys k0+32hh+{4quad'+r}
        float* pb = p[2 * hh + 1];  // keys k0+32hh+16+{4quad'+r}
        uint32_t e0 = pack2bf(pa[0], pa[1]);
        uint32_t e1 = pack2bf(pa[2], pa[3]);
        uint32_t e2 = pack2bf(pb[0], pb[1]);
        uint32_t e3 = pack2bf(pb[2], pb[3]);
        uint32_t a0 = (uint32_t)__shfl((int)e0, L0);
        uint32_t b0 = (uint32_t)__shfl((int)e1, L0);
        uint32_t a1 = (uint32_t)__shfl((int)e0, L0 + 16);
        uint32_t b1 = (uint32_t)__shfl((int)e1, L0 + 16);
        uint32_t c0 = (uint32_t)__shfl((int)e2, L0);
        uint32_t d0 = (uint32_t)__shfl((int)e3, L0);
        uint32_t c1 = (uint32_t)__shfl((int)e2, L0 + 16);
        uint32_t d1 = (uint32_t)__shfl((int)e3, L0 + 16);
        union { uint32_t u[4]; bf16x8 v; } bp;
        bp.u[0] = hilo ? c0 : a0;
        bp.u[1] = hilo ? d0 : b0;
        bp.u[2] = hilo ? c1 : a1;
        bp.u[3] = hilo ? d1 : b1;
#pragma unroll
        for (int db = 0; db < 4; ++db)
          acc[db] = __builtin_amdgcn_mfma_f32_16x16x32_bf16(av[db][hh], bp.v, acc[db], 0, 0, 0);
      }
    }
    __syncthreads();                // protect LDS before next stage
  }

  // --- finalize both subtiles: quad-reduce l, normalize, 8B stores ---
#pragma unroll
  for (int s = 0; s < 2; ++s) {
    float l = s ? l1 : l0;
    f32x4* acc = s ? acc1 : acc0;
    int qt = s ? qt1 : qt0;
    l += __shfl_xor(l, 16);
    l += __shfl_xor(l, 32);
    float inv = 1.0f / l;
    size_t rowbase = ((size_t)(b * 512 + qt + c)) * 1024 + h * 64 + (quad << 2);
#pragma unroll
    for (int db = 0; db < 4; ++db) {
      s16x4 o;
#pragma unroll
      for (int r = 0; r < 4; ++r) o[r] = f2bf(acc[db][r] * inv);
      *(s16x4*)&ctx[rowbase + db * 16] = o;
    }
  }
}

// ---------------------------------------------------------------------------
// Output projection v2: out = ctx @ w_o^T + b_o  (fp32 out).
//   R5 post-mortem: 256 blocks = 1 block/CU left every barrier drain fully
//   exposed. Retile 64x64, BK=64 -> 1024 blocks = 4 blocks/CU of drain
//   overlap; 16KB LDS, ~80 VGPR, launch_bounds(256,4). Per wave-iter:
//   8 MFMA, 8 ds_read_b128, 4 async16; 16 iterations.
// ---------------------------------------------------------------------------
__global__ __launch_bounds__(256, 4) void gemm_out(const short* __restrict__ ws,
                                                   const float* __restrict__ bias,
                                                   float* __restrict__ out) {
  __shared__ __align__(16) short As[4096];   // 64 rows x 64 k, 8 chunks
  __shared__ __align__(16) short Bs[4096];
  int bx = blockIdx.x;              // 0..1023
  int mt = bx >> 4, nt = bx & 15;
  int m0 = mt << 6, n0 = nt << 6;
  const short* A  = ws + OFF_CT;
  const short* Bw = ws + OFF_WO;
  int t = threadIdx.x, lane = t & 63, wvi = t >> 6;
  int c = lane & 15, quad = lane >> 4;
  int wm = wvi >> 1, wn = wvi & 1;   // wave tile 32m x 32n
  f32x4 acc[2][2] = {};

  for (int kk = 0; kk < 1024; kk += 64) {
    // --- stage 16 chunks (8 A + 8 B), 4 per wave ---
#pragma unroll
    for (int i = 0; i < 4; ++i) {
      int ch = wvi * 4 + i;
      if (ch < 8) {
        int mg = ch >> 1, kh = ch & 1;
        async16(&As[ch << 9], A + (m0 + mg * 16 + c) * 1024 + kk + kh * 32 + (quad << 3));
      } else {
        int cb = ch - 8, mg = cb >> 1, kh = cb & 1;
        async16(&Bs[cb << 9], Bw + (n0 + mg * 16 + c) * 1024 + kk + kh * 32 + (quad << 3));
      }
    }
    __syncthreads();

    bf16x8 af[2][2], bfr[2][2];
#pragma unroll
    for (int i = 0; i < 2; ++i)
#pragma unroll
      for (int kh = 0; kh < 2; ++kh) {
        af[i][kh]  = *(const bf16x8*)&As[((((wm * 2 + i) << 1) + kh) << 9) + lane * 8];
        bfr[i][kh] = *(const bf16x8*)&Bs[((((wn * 2 + i) << 1) + kh) << 9) + lane * 8];
      }
#pragma unroll
    for (int kh = 0; kh < 2; ++kh)
#pragma unroll
      for (int i = 0; i < 2; ++i)
#pragma unroll
        for (int j = 0; j < 2; ++j)
          acc[i][j] = __builtin_amdgcn_mfma_f32_16x16x32_bf16(af[i][kh], bfr[j][kh], acc[i][j], 0, 0, 0);
    __syncthreads();
  }

#pragma unroll
  for (int j = 0; j < 2; ++j) {
    int n = n0 + wn * 32 + j * 16 + c;
    float bj = bias[n];
#pragma unroll
    for (int i = 0; i < 2; ++i) {
      int mq = m0 + wm * 32 + i * 16 + quad * 4;
#pragma unroll
      for (int r = 0; r < 4; ++r)
        out[(size_t)(mq + r) * 1024 + n] = acc[i][j][r] + bj;
    }
  }
}

extern "C" void kernel_launch(void* const* d_in, const int* in_sizes, int n_in,
                              void* d_out, int out_size, void* d_ws, size_t ws_size,
                              hipStream_t stream) {
  (void)in_sizes; (void)n_in; (void)out_size; (void)ws_size;  // needs 48 MB of d_ws
  const float* x  = (const float*)d_in[0];
  const float* wq = (const float*)d_in[1];
  const float* wk = (const float*)d_in[2];
  const float* wv = (const float*)d_in[3];
  const float* wo = (const float*)d_in[4];
  const float* bo = (const float*)d_in[5];
  short* ws = (short*)d_ws;
  float* out = (float*)d_out;

  cvt5<<<8192, 256, 0, stream>>>(x, wq, wk, wv, wo, ws);
  gemm_qkv<<<768, 256, 0, stream>>>(ws);
  attn<<<512, 256, 0, stream>>>(ws);
  gemm_out<<<1024, 256, 0, stream>>>(ws, bo, out);
}

// Round 7
// 184.548 us; speedup vs baseline: 1.0570x; 1.0505x over previous
//
#include <hip/hip_runtime.h>
#include <stdint.h>
#include <math.h>

// Problem constants
#define NB_B 8
#define NB_S 512
#define NB_D 1024
#define NB_H 16
#define NB_HD 64
#define NP 196            // image patches: bidirectional prefix block
#define MTOT 4096         // B*S

// Workspace layout (offsets in bf16/short elements). Total 25165824 shorts = 48 MB.
#define OFF_XB 0
#define OFF_WQ 4194304
#define OFF_WK 5242880
#define OFF_WV 6291456
#define OFF_WO 7340032
#define OFF_Q  8388608
#define OFF_K  12582912
#define OFF_VT 16777216
#define OFF_CT 20971520

typedef __attribute__((ext_vector_type(8))) short bf16x8;
typedef __attribute__((ext_vector_type(4))) float f32x4;
typedef __attribute__((ext_vector_type(4))) short s16x4;

__device__ __forceinline__ short f2bf(float f) {
  union { float f; uint32_t u; } c; c.f = f;
  uint32_t r = (c.u + 0x7fffu + ((c.u >> 16) & 1u)) >> 16;   // RNE
  return (short)r;
}

// pack two fp32 -> one dword of two bf16 (round-half-up; inputs are positive
// softmax weights or zeros, so the cheap +0x8000 rounding is safe)
__device__ __forceinline__ uint32_t pack2bf(float lo, float hi) {
  uint32_t ulo = __float_as_uint(lo) + 0x8000u;
  uint32_t uhi = __float_as_uint(hi) + 0x8000u;
  return __builtin_amdgcn_perm(uhi, ulo, 0x07060302u);  // [bf16(hi)|bf16(lo)]
}

__device__ __forceinline__ void async16(void* lds, const void* g) {
  // global -> LDS direct copy, 16B per lane; LDS dest = uniform base + lane*16
  __builtin_amdgcn_global_load_lds(
      (const __attribute__((address_space(1))) void*)g,
      (__attribute__((address_space(3))) void*)lds, 16, 0, 0);
}

// ---------------------------------------------------------------------------
// fp32 -> bf16 conversion for x and the 4 weight matrices (one fused launch).
// w_q gets the 1/sqrt(hd)=0.125 softmax scale folded in (exact pow2 in bf16).
// ---------------------------------------------------------------------------
__global__ __launch_bounds__(256) void cvt5(const float* __restrict__ x,
                                            const float* __restrict__ wq,
                                            const float* __restrict__ wk,
                                            const float* __restrict__ wv,
                                            const float* __restrict__ wo,
                                            short* __restrict__ ws) {
  int b = blockIdx.x, t = threadIdx.x;
  const float* src; short* dst; float scale;
  if (b < 4096) { src = x + b * 1024; dst = ws + OFF_XB + b * 1024; scale = 1.0f; }
  else {
    int wb = b - 4096, wi = wb >> 10, r = wb & 1023;
    switch (wi) {
      case 0:  src = wq + r * 1024; dst = ws + OFF_WQ + r * 1024; scale = 0.125f; break;
      case 1:  src = wk + r * 1024; dst = ws + OFF_WK + r * 1024; scale = 1.0f;   break;
      case 2:  src = wv + r * 1024; dst = ws + OFF_WV + r * 1024; scale = 1.0f;   break;
      default: src = wo + r * 1024; dst = ws + OFF_WO + r * 1024; scale = 1.0f;   break;
    }
  }
  int i = t << 2;
  float4 v = *(const float4*)(src + i);
  s16x4 o;
  o[0] = f2bf(v.x * scale); o[1] = f2bf(v.y * scale);
  o[2] = f2bf(v.z * scale); o[3] = f2bf(v.w * scale);
  *(s16x4*)(dst + i) = o;
}

// ---------------------------------------------------------------------------
// QKV projection — exact R4 structure (best measured: 56us). 128x128 tile,
// BK=32, 768 blocks (3/CU), 4 waves each 64x64. R5/R6 variants (fused wide
// tile, BK=64) both regressed/neutral: this family is latency-plateaued at
// ~56-60us regardless of BK/fusion (staged-byte invariance, see R6 notes).
// ---------------------------------------------------------------------------
__global__ __launch_bounds__(256, 2) void gemm_qkv(short* __restrict__ ws) {
  __shared__ __align__(16) short As[4096];   // 128x32 bf16
  __shared__ __align__(16) short Bs[4096];
  int bx = blockIdx.x;              // 0..767
  int wsel = bx >> 8;               // 0=Q 1=K 2=V
  int tile = bx & 255;
  int mt = tile >> 3, nt = tile & 7;
  int m0 = mt << 7, n0 = nt << 7;
  const short* A  = ws + OFF_XB;
  const short* Bw = ws + (wsel == 0 ? OFF_WQ : (wsel == 1 ? OFF_WK : OFF_WV));
  int t = threadIdx.x, lane = t & 63, wvi = t >> 6;
  int c = lane & 15, quad = lane >> 4;
  int wm = wvi >> 1, wn = wvi & 1;
  f32x4 acc[4][4] = {};

  for (int kk = 0; kk < 1024; kk += 32) {
#pragma unroll
    for (int i = 0; i < 2; ++i) {
      int ch = wvi * 2 + i;         // wave-uniform chunk id (mb / nb block)
      const short* ga = A  + (m0 + ch * 16 + c) * 1024 + kk + (quad << 3);
      async16(&As[ch << 9], ga);
      const short* gb = Bw + (n0 + ch * 16 + c) * 1024 + kk + (quad << 3);
      async16(&Bs[ch << 9], gb);
    }
    __syncthreads();                // drains vmcnt for global_load_lds
    bf16x8 af[4], bfr[4];
#pragma unroll
    for (int i = 0; i < 4; ++i) af[i]  = *(const bf16x8*)&As[((wm * 4 + i) * 64 + lane) * 8];
#pragma unroll
    for (int j = 0; j < 4; ++j) bfr[j] = *(const bf16x8*)&Bs[((wn * 4 + j) * 64 + lane) * 8];
#pragma unroll
    for (int i = 0; i < 4; ++i)
#pragma unroll
      for (int j = 0; j < 4; ++j)
        acc[i][j] = __builtin_amdgcn_mfma_f32_16x16x32_bf16(af[i], bfr[j], acc[i][j], 0, 0, 0);
    __syncthreads();                // protect LDS before next stage
  }

  short* outp = ws + (wsel == 0 ? OFF_Q : (wsel == 1 ? OFF_K : OFF_VT));
#pragma unroll
  for (int i = 0; i < 4; ++i) {
#pragma unroll
    for (int j = 0; j < 4; ++j) {
      int n = n0 + wn * 64 + j * 16 + c;        // output feature
      int h = n >> 6, d = n & 63;
      int mq = m0 + wm * 64 + i * 16 + quad * 4; // first of the 4 rows (reg dim)
      int bb = mq >> 9, s = mq & 511;
      if (wsel < 2) {
        // [B,H,S,hd]
#pragma unroll
        for (int r = 0; r < 4; ++r)
          outp[((bb * 16 + h) * 512 + (s + r)) * 64 + d] = f2bf(acc[i][j][r]);
      } else {
        // V transposed: [B,H,hd,S]; the 4 regs are 4 consecutive s -> 8B store
        s16x4 o;
#pragma unroll
        for (int r = 0; r < 4; ++r) o[r] = f2bf(acc[i][j][r]);
        *(s16x4*)&outp[((bb * 16 + h) * 64 + d) * 512 + s] = o;
      }
    }
  }
}

// ---------------------------------------------------------------------------
// Attention v4 (block-cooperative flash, LDS-staged K/V) — unchanged from R4.
// ---------------------------------------------------------------------------
__global__ __launch_bounds__(256, 2) void attn(short* __restrict__ ws) {
  __shared__ __align__(16) short Kb[4096];   // 64 keys x 64 d, 8 frag chunks
  __shared__ __align__(16) short Vb[4096];   // 64 d x 64 keys, 8 frag chunks
  int bi = blockIdx.x;              // 0..511
  int bh = bi >> 2, qcr = bi & 3;
  int qc = (qcr + bh + 2 * (bh >> 6)) & 3;   // rotate so CU pairs mix light/heavy
  int t = threadIdx.x, lane = t & 63, wvi = t >> 6;
  int c = lane & 15, quad = lane >> 4;
  const short* Qh  = ws + OFF_Q  + bh * (512 * 64);
  const short* Kh  = ws + OFF_K  + bh * (512 * 64);
  const short* Vth = ws + OFF_VT + bh * (64 * 512);
  short* ctx = ws + OFF_CT;
  int b = bh >> 4, h = bh & 15;

  int qt0 = qc * 128 + wvi * 32;    // two 16-row subtiles per wave
  int qt1 = qt0 + 16;
  int kn0 = (qt0 + 16 > NP) ? (qt0 + 16) : NP;
  int kn1 = (qt1 + 16 > NP) ? (qt1 + 16) : NP;
  int knb = (qc * 128 + 128 > NP) ? (qc * 128 + 128) : NP;
  int NCH = (knb + 63) >> 6;        // 64-key chunks staged by the block

  // Q^T B-frags for both subtiles: [n=q=lane&15][k=d=quad*8+j] (+32 frag 1)
  bf16x8 q00 = *(const bf16x8*)(Qh + (qt0 + c) * 64 + (quad << 3));
  bf16x8 q01 = *(const bf16x8*)(Qh + (qt0 + c) * 64 + 32 + (quad << 3));
  bf16x8 q10 = *(const bf16x8*)(Qh + (qt1 + c) * 64 + (quad << 3));
  bf16x8 q11 = *(const bf16x8*)(Qh + (qt1 + c) * 64 + 32 + (quad << 3));

  f32x4 acc0[4] = {}, acc1[4] = {}; // ctx^T accumulators per subtile
  float l0 = 0.0f, l1 = 0.0f;       // in-lane softmax denominators
  int L0 = c + ((quad & 1) << 5);   // transpose source lane
  bool hilo = quad >= 2;

  for (int ch = 0; ch < NCH; ++ch) {
    int k0 = ch << 6;
    // --- stage K[k0..k0+63][0..63] and V^T[0..63][k0..k0+63], frag-swizzled.
    {
      const short* gk = Kh + (k0 + wvi * 16 + c) * 64 + (quad << 3);
      async16(&Kb[(wvi * 2 + 0) << 9], gk);
      async16(&Kb[(wvi * 2 + 1) << 9], gk + 32);
      const short* gv = Vth + (wvi * 16 + c) * 512 + k0 + (quad << 3);
      async16(&Vb[(wvi * 2 + 0) << 9], gv);
      async16(&Vb[(wvi * 2 + 1) << 9], gv + 32);
    }
    __syncthreads();                // drains vmcnt for global_load_lds

    // K A-frags [m=key16][k=d] and V^T A-frags [m=d16][k=key32+..]
    bf16x8 ak[4][2], av[4][2];
#pragma unroll
    for (int mb = 0; mb < 4; ++mb)
#pragma unroll
      for (int f = 0; f < 2; ++f) {
        ak[mb][f] = *(const bf16x8*)&Kb[((mb * 2 + f) << 9) + lane * 8];
        av[mb][f] = *(const bf16x8*)&Vb[((mb * 2 + f) << 9) + lane * 8];
      }

#pragma unroll
    for (int s = 0; s < 2; ++s) {
      int qt = s ? qt1 : qt0;
      int kn = s ? kn1 : kn0;
      if (k0 >= kn) continue;       // subtile finished (other subtile may not be)
      bf16x8 bq0 = s ? q10 : q00;
      bf16x8 bq1 = s ? q11 : q01;
      f32x4* acc = s ? acc1 : acc0;

      // --- S^T = K . Q^T : 4 m-blocks of 16 keys ---
      float p[4][4];
#pragma unroll
      for (int mb = 0; mb < 4; ++mb) {
        f32x4 st = {};
        st = __builtin_amdgcn_mfma_f32_16x16x32_bf16(ak[mb][0], bq0, st, 0, 0, 0);
        st = __builtin_amdgcn_mfma_f32_16x16x32_bf16(ak[mb][1], bq1, st, 0, 0, 0);
#pragma unroll
        for (int r = 0; r < 4; ++r) p[mb][r] = __expf(st[r]);
      }

      // --- prefix/causal mask (only chunks that can contain invalid keys) ---
      if ((k0 + 64 > NP) && (k0 + 64 > qt + 1)) {
        int row = qt + c;
#pragma unroll
        for (int mb = 0; mb < 4; ++mb)
#pragma unroll
          for (int r = 0; r < 4; ++r) {
            int key = k0 + mb * 16 + (quad << 2) + r;
            bool v = (row < NP) ? (key < NP) : (key <= row);
            p[mb][r] = v ? p[mb][r] : 0.0f;
          }
      }
      float ls = 0.0f;
#pragma unroll
      for (int mb = 0; mb < 4; ++mb)
#pragma unroll
        for (int r = 0; r < 4; ++r) ls += p[mb][r];
      if (s) l1 += ls; else l0 += ls;

      // --- per 32-key half: transpose to B-frag (R3-verified), then PV ---
#pragma unroll
      for (int hh = 0; hh < 2; ++hh) {
        float* pa = p[2 * hh];      // keys k0+32hh+{4quad'+r}
        float* pb = p[2 * hh + 1];  // keys k0+32hh+16+{4quad'+r}
        uint32_t e0 = pack2bf(pa[0], pa[1]);
        uint32_t e1 = pack2bf(pa[2], pa[3]);
        uint32_t e2 = pack2bf(pb[0], pb[1]);
        uint32_t e3 = pack2bf(pb[2], pb[3]);
        uint32_t a0 = (uint32_t)__shfl((int)e0, L0);
        uint32_t b0 = (uint32_t)__shfl((int)e1, L0);
        uint32_t a1 = (uint32_t)__shfl((int)e0, L0 + 16);
        uint32_t b1 = (uint32_t)__shfl((int)e1, L0 + 16);
        uint32_t c0 = (uint32_t)__shfl((int)e2, L0);
        uint32_t d0 = (uint32_t)__shfl((int)e3, L0);
        uint32_t c1 = (uint32_t)__shfl((int)e2, L0 + 16);
        uint32_t d1 = (uint32_t)__shfl((int)e3, L0 + 16);
        union { uint32_t u[4]; bf16x8 v; } bp;
        bp.u[0] = hilo ? c0 : a0;
        bp.u[1] = hilo ? d0 : b0;
        bp.u[2] = hilo ? c1 : a1;
        bp.u[3] = hilo ? d1 : b1;
#pragma unroll
        for (int db = 0; db < 4; ++db)
          acc[db] = __builtin_amdgcn_mfma_f32_16x16x32_bf16(av[db][hh], bp.v, acc[db], 0, 0, 0);
      }
    }
    __syncthreads();                // protect LDS before next stage
  }

  // --- finalize both subtiles: quad-reduce l, normalize, 8B stores ---
#pragma unroll
  for (int s = 0; s < 2; ++s) {
    float l = s ? l1 : l0;
    f32x4* acc = s ? acc1 : acc0;
    int qt = s ? qt1 : qt0;
    l += __shfl_xor(l, 16);
    l += __shfl_xor(l, 32);
    float inv = 1.0f / l;
    size_t rowbase = ((size_t)(b * 512 + qt + c)) * 1024 + h * 64 + (quad << 2);
#pragma unroll
    for (int db = 0; db < 4; ++db) {
      s16x4 o;
#pragma unroll
      for (int r = 0; r < 4; ++r) o[r] = f2bf(acc[db][r] * inv);
      *(s16x4*)&ctx[rowbase + db * 16] = o;
    }
  }
}

// ---------------------------------------------------------------------------
// Output projection v3: out = ctx @ w_o^T + b_o  (fp32 out).
//   64m x 128n tiles, BK=64 -> 512 blocks (fills all 512 block slots, 16
//   iterations). Staged 196 MB total (vs 262 MB for 64x64/BK64), per-CU
//   block-iters 32 (vs 128). 4 waves, wave-tile 32m x 64n: acc 2x4,
//   per wave-iter 16 MFMA : 12 ds_read_b128 : 6 async16. LDS 24 KB.
// ---------------------------------------------------------------------------
__global__ __launch_bounds__(256, 2) void gemm_out(const short* __restrict__ ws,
                                                   const float* __restrict__ bias,
                                                   float* __restrict__ out) {
  __shared__ __align__(16) short As[4096];   // 64 rows x 64 k  = 8 chunks
  __shared__ __align__(16) short Bs[8192];   // 128 rows x 64 k = 16 chunks
  int bx = blockIdx.x;              // 0..511
  int mt = bx >> 3, nt = bx & 7;
  int m0 = mt << 6, n0 = nt << 7;
  const short* A  = ws + OFF_CT;
  const short* Bw = ws + OFF_WO;
  int t = threadIdx.x, lane = t & 63, wvi = t >> 6;
  int c = lane & 15, quad = lane >> 4;
  int wm = wvi >> 1, wn = wvi & 1;   // wave tile 32m x 64n
  f32x4 acc[2][4] = {};

  for (int kk = 0; kk < 1024; kk += 64) {
    // --- stage 24 chunks (A 8 + B 16), 6 per wave, frag-swizzled ---
    // chunk = mg*2+kh: rows [16*mg,+16), k [kk+32*kh,+32)
#pragma unroll
    for (int i = 0; i < 6; ++i) {
      int ch = wvi * 6 + i;
      if (ch < 8) {
        int mg = ch >> 1, kh = ch & 1;
        async16(&As[ch << 9], A + (m0 + mg * 16 + c) * 1024 + kk + kh * 32 + (quad << 3));
      } else {
        int cb = ch - 8, mg = cb >> 1, kh = cb & 1;
        async16(&Bs[cb << 9], Bw + (n0 + mg * 16 + c) * 1024 + kk + kh * 32 + (quad << 3));
      }
    }
    __syncthreads();                // drains vmcnt for global_load_lds

    bf16x8 af[2][2], bfr[4][2];
#pragma unroll
    for (int i = 0; i < 2; ++i)
#pragma unroll
      for (int kh = 0; kh < 2; ++kh)
        af[i][kh] = *(const bf16x8*)&As[((((wm * 2 + i) << 1) + kh) << 9) + lane * 8];
#pragma unroll
    for (int j = 0; j < 4; ++j)
#pragma unroll
      for (int kh = 0; kh < 2; ++kh)
        bfr[j][kh] = *(const bf16x8*)&Bs[((((wn * 4 + j) << 1) + kh) << 9) + lane * 8];
#pragma unroll
    for (int kh = 0; kh < 2; ++kh)
#pragma unroll
      for (int i = 0; i < 2; ++i)
#pragma unroll
        for (int j = 0; j < 4; ++j)
          acc[i][j] = __builtin_amdgcn_mfma_f32_16x16x32_bf16(af[i][kh], bfr[j][kh], acc[i][j], 0, 0, 0);
    __syncthreads();                // protect LDS before next stage
  }

#pragma unroll
  for (int j = 0; j < 4; ++j) {
    int n = n0 + wn * 64 + j * 16 + c;
    float bj = bias[n];
#pragma unroll
    for (int i = 0; i < 2; ++i) {
      int mq = m0 + wm * 32 + i * 16 + quad * 4;
#pragma unroll
      for (int r = 0; r < 4; ++r)
        out[(size_t)(mq + r) * 1024 + n] = acc[i][j][r] + bj;
    }
  }
}

extern "C" void kernel_launch(void* const* d_in, const int* in_sizes, int n_in,
                              void* d_out, int out_size, void* d_ws, size_t ws_size,
                              hipStream_t stream) {
  (void)in_sizes; (void)n_in; (void)out_size; (void)ws_size;  // needs 48 MB of d_ws
  const float* x  = (const float*)d_in[0];
  const float* wq = (const float*)d_in[1];
  const float* wk = (const float*)d_in[2];
  const float* wv = (const float*)d_in[3];
  const float* wo = (const float*)d_in[4];
  const float* bo = (const float*)d_in[5];
  short* ws = (short*)d_ws;
  float* out = (float*)d_out;

  cvt5<<<8192, 256, 0, stream>>>(x, wq, wk, wv, wo, ws);
  gemm_qkv<<<768, 256, 0, stream>>>(ws);
  attn<<<512, 256, 0, stream>>>(ws);
  gemm_out<<<512, 256, 0, stream>>>(ws, bo, out);
}

// Round 8
// 182.256 us; speedup vs baseline: 1.0703x; 1.0126x over previous
//
#include <hip/hip_runtime.h>
#include <stdint.h>
#include <math.h>

// Problem constants
#define NB_B 8
#define NB_S 512
#define NB_D 1024
#define NB_H 16
#define NB_HD 64
#define NP 196            // image patches: bidirectional prefix block
#define MTOT 4096         // B*S

// Workspace layout (offsets in bf16/short elements). Total 25165824 shorts = 48 MB.
#define OFF_XB 0
#define OFF_WQ 4194304
#define OFF_WK 5242880
#define OFF_WV 6291456
#define OFF_WO 7340032
#define OFF_Q  8388608
#define OFF_K  12582912
#define OFF_VT 16777216
#define OFF_CT 20971520

typedef __attribute__((ext_vector_type(8))) short bf16x8;
typedef __attribute__((ext_vector_type(4))) float f32x4;
typedef __attribute__((ext_vector_type(4))) short s16x4;

__device__ __forceinline__ short f2bf(float f) {
  union { float f; uint32_t u; } c; c.f = f;
  uint32_t r = (c.u + 0x7fffu + ((c.u >> 16) & 1u)) >> 16;   // RNE
  return (short)r;
}

// pack two fp32 -> one dword of two bf16 (round-half-up; inputs are positive
// softmax weights or zeros, so the cheap +0x8000 rounding is safe)
__device__ __forceinline__ uint32_t pack2bf(float lo, float hi) {
  uint32_t ulo = __float_as_uint(lo) + 0x8000u;
  uint32_t uhi = __float_as_uint(hi) + 0x8000u;
  return __builtin_amdgcn_perm(uhi, ulo, 0x07060302u);  // [bf16(hi)|bf16(lo)]
}

__device__ __forceinline__ void async16(void* lds, const void* g) {
  // global -> LDS direct copy, 16B per lane; LDS dest = uniform base + lane*16
  __builtin_amdgcn_global_load_lds(
      (const __attribute__((address_space(1))) void*)g,
      (__attribute__((address_space(3))) void*)lds, 16, 0, 0);
}

// raw workgroup barrier WITHOUT the vmcnt(0) drain __syncthreads() implies;
// memory clobber pins all memory ops (async16 issues, ds_reads) on their side.
__device__ __forceinline__ void barrier_raw() {
  asm volatile("s_barrier" ::: "memory");
}

// ---------------------------------------------------------------------------
// fp32 -> bf16 conversion for x and the 4 weight matrices (one fused launch).
// w_q gets the 1/sqrt(hd)=0.125 softmax scale folded in (exact pow2 in bf16).
// ---------------------------------------------------------------------------
__global__ __launch_bounds__(256) void cvt5(const float* __restrict__ x,
                                            const float* __restrict__ wq,
                                            const float* __restrict__ wk,
                                            const float* __restrict__ wv,
                                            const float* __restrict__ wo,
                                            short* __restrict__ ws) {
  int b = blockIdx.x, t = threadIdx.x;
  const float* src; short* dst; float scale;
  if (b < 4096) { src = x + b * 1024; dst = ws + OFF_XB + b * 1024; scale = 1.0f; }
  else {
    int wb = b - 4096, wi = wb >> 10, r = wb & 1023;
    switch (wi) {
      case 0:  src = wq + r * 1024; dst = ws + OFF_WQ + r * 1024; scale = 0.125f; break;
      case 1:  src = wk + r * 1024; dst = ws + OFF_WK + r * 1024; scale = 1.0f;   break;
      case 2:  src = wv + r * 1024; dst = ws + OFF_WV + r * 1024; scale = 1.0f;   break;
      default: src = wo + r * 1024; dst = ws + OFF_WO + r * 1024; scale = 1.0f;   break;
    }
  }
  int i = t << 2;
  float4 v = *(const float4*)(src + i);
  s16x4 o;
  o[0] = f2bf(v.x * scale); o[1] = f2bf(v.y * scale);
  o[2] = f2bf(v.z * scale); o[3] = f2bf(v.w * scale);
  *(s16x4*)(dst + i) = o;
}

// ---------------------------------------------------------------------------
// QKV projection v4: R4 tiling (128x128, BK=32, 768 blocks, 4 waves x 64x64)
// + software-pipelined LDS double-buffer with RAW s_barrier and partial
// s_waitcnt vmcnt(4). Iteration it issues the DMAs for it+1 BEFORE its own
// barrier, so they stay in flight across it (the __syncthreads vmcnt(0)
// drain was ~75% of this kernel's time: MfmaUtil 17 / VALU 9 / HBM 14).
// WAR safety: buf b staged at it is the one last READ at it-1; the tail
// barrier of it-1 orders all reads before the stage. Uniform control flow
// keeps barrier counts equal across waves.
// ---------------------------------------------------------------------------
__global__ __launch_bounds__(256, 2) void gemm_qkv(short* __restrict__ ws) {
  __shared__ __align__(16) short As[2][4096];   // 128x32 bf16 per buffer
  __shared__ __align__(16) short Bs[2][4096];
  int bx = blockIdx.x;              // 0..767
  int wsel = bx >> 8;               // 0=Q 1=K 2=V
  int tile = bx & 255;
  int mt = tile >> 3, nt = tile & 7;
  int m0 = mt << 7, n0 = nt << 7;
  const short* A  = ws + OFF_XB;
  const short* Bw = ws + (wsel == 0 ? OFF_WQ : (wsel == 1 ? OFF_WK : OFF_WV));
  int t = threadIdx.x, lane = t & 63, wvi = t >> 6;
  int c = lane & 15, quad = lane >> 4;
  int wm = wvi >> 1, wn = wvi & 1;
  f32x4 acc[4][4] = {};

  auto stage = [&](int buf, int kk) {   // 4 async16 per wave (2 A + 2 B)
#pragma unroll
    for (int i = 0; i < 2; ++i) {
      int ch = wvi * 2 + i;
      async16(&As[buf][ch << 9], A  + (m0 + ch * 16 + c) * 1024 + kk + (quad << 3));
      async16(&Bs[buf][ch << 9], Bw + (n0 + ch * 16 + c) * 1024 + kk + (quad << 3));
    }
  };

  stage(0, 0);
  for (int it = 0; it < 32; ++it) {
    int buf = it & 1;
    if (it < 31) {
      stage(buf ^ 1, (it + 1) * 32);
      asm volatile("s_waitcnt vmcnt(4)" ::: "memory");  // own current-buf loads done
    } else {
      asm volatile("s_waitcnt vmcnt(0)" ::: "memory");
    }
    barrier_raw();                   // all waves' current-buf chunks visible
    bf16x8 af[4], bfr[4];
#pragma unroll
    for (int i = 0; i < 4; ++i) af[i]  = *(const bf16x8*)&As[buf][((wm * 4 + i) << 9) + lane * 8];
#pragma unroll
    for (int j = 0; j < 4; ++j) bfr[j] = *(const bf16x8*)&Bs[buf][((wn * 4 + j) << 9) + lane * 8];
#pragma unroll
    for (int i = 0; i < 4; ++i)
#pragma unroll
      for (int j = 0; j < 4; ++j)
        acc[i][j] = __builtin_amdgcn_mfma_f32_16x16x32_bf16(af[i], bfr[j], acc[i][j], 0, 0, 0);
    barrier_raw();                   // all reads of buf done -> safe to re-stage
  }

  short* outp = ws + (wsel == 0 ? OFF_Q : (wsel == 1 ? OFF_K : OFF_VT));
#pragma unroll
  for (int i = 0; i < 4; ++i) {
#pragma unroll
    for (int j = 0; j < 4; ++j) {
      int n = n0 + wn * 64 + j * 16 + c;        // output feature
      int h = n >> 6, d = n & 63;
      int mq = m0 + wm * 64 + i * 16 + quad * 4; // first of the 4 rows (reg dim)
      int bb = mq >> 9, s = mq & 511;
      if (wsel < 2) {
        // [B,H,S,hd]
#pragma unroll
        for (int r = 0; r < 4; ++r)
          outp[((bb * 16 + h) * 512 + (s + r)) * 64 + d] = f2bf(acc[i][j][r]);
      } else {
        // V transposed: [B,H,hd,S]; the 4 regs are 4 consecutive s -> 8B store
        s16x4 o;
#pragma unroll
        for (int r = 0; r < 4; ++r) o[r] = f2bf(acc[i][j][r]);
        *(s16x4*)&outp[((bb * 16 + h) * 64 + d) * 512 + s] = o;
      }
    }
  }
}

// ---------------------------------------------------------------------------
// Attention v4 (block-cooperative flash, LDS-staged K/V) — unchanged from R4.
// ---------------------------------------------------------------------------
__global__ __launch_bounds__(256, 2) void attn(short* __restrict__ ws) {
  __shared__ __align__(16) short Kb[4096];   // 64 keys x 64 d, 8 frag chunks
  __shared__ __align__(16) short Vb[4096];   // 64 d x 64 keys, 8 frag chunks
  int bi = blockIdx.x;              // 0..511
  int bh = bi >> 2, qcr = bi & 3;
  int qc = (qcr + bh + 2 * (bh >> 6)) & 3;   // rotate so CU pairs mix light/heavy
  int t = threadIdx.x, lane = t & 63, wvi = t >> 6;
  int c = lane & 15, quad = lane >> 4;
  const short* Qh  = ws + OFF_Q  + bh * (512 * 64);
  const short* Kh  = ws + OFF_K  + bh * (512 * 64);
  const short* Vth = ws + OFF_VT + bh * (64 * 512);
  short* ctx = ws + OFF_CT;
  int b = bh >> 4, h = bh & 15;

  int qt0 = qc * 128 + wvi * 32;    // two 16-row subtiles per wave
  int qt1 = qt0 + 16;
  int kn0 = (qt0 + 16 > NP) ? (qt0 + 16) : NP;
  int kn1 = (qt1 + 16 > NP) ? (qt1 + 16) : NP;
  int knb = (qc * 128 + 128 > NP) ? (qc * 128 + 128) : NP;
  int NCH = (knb + 63) >> 6;        // 64-key chunks staged by the block

  // Q^T B-frags for both subtiles: [n=q=lane&15][k=d=quad*8+j] (+32 frag 1)
  bf16x8 q00 = *(const bf16x8*)(Qh + (qt0 + c) * 64 + (quad << 3));
  bf16x8 q01 = *(const bf16x8*)(Qh + (qt0 + c) * 64 + 32 + (quad << 3));
  bf16x8 q10 = *(const bf16x8*)(Qh + (qt1 + c) * 64 + (quad << 3));
  bf16x8 q11 = *(const bf16x8*)(Qh + (qt1 + c) * 64 + 32 + (quad << 3));

  f32x4 acc0[4] = {}, acc1[4] = {}; // ctx^T accumulators per subtile
  float l0 = 0.0f, l1 = 0.0f;       // in-lane softmax denominators
  int L0 = c + ((quad & 1) << 5);   // transpose source lane
  bool hilo = quad >= 2;

  for (int ch = 0; ch < NCH; ++ch) {
    int k0 = ch << 6;
    // --- stage K[k0..k0+63][0..63] and V^T[0..63][k0..k0+63], frag-swizzled.
    {
      const short* gk = Kh + (k0 + wvi * 16 + c) * 64 + (quad << 3);
      async16(&Kb[(wvi * 2 + 0) << 9], gk);
      async16(&Kb[(wvi * 2 + 1) << 9], gk + 32);
      const short* gv = Vth + (wvi * 16 + c) * 512 + k0 + (quad << 3);
      async16(&Vb[(wvi * 2 + 0) << 9], gv);
      async16(&Vb[(wvi * 2 + 1) << 9], gv + 32);
    }
    __syncthreads();                // drains vmcnt for global_load_lds

    // K A-frags [m=key16][k=d] and V^T A-frags [m=d16][k=key32+..]
    bf16x8 ak[4][2], av[4][2];
#pragma unroll
    for (int mb = 0; mb < 4; ++mb)
#pragma unroll
      for (int f = 0; f < 2; ++f) {
        ak[mb][f] = *(const bf16x8*)&Kb[((mb * 2 + f) << 9) + lane * 8];
        av[mb][f] = *(const bf16x8*)&Vb[((mb * 2 + f) << 9) + lane * 8];
      }

#pragma unroll
    for (int s = 0; s < 2; ++s) {
      int qt = s ? qt1 : qt0;
      int kn = s ? kn1 : kn0;
      if (k0 >= kn) continue;       // subtile finished (other subtile may not be)
      bf16x8 bq0 = s ? q10 : q00;
      bf16x8 bq1 = s ? q11 : q01;
      f32x4* acc = s ? acc1 : acc0;

      // --- S^T = K . Q^T : 4 m-blocks of 16 keys ---
      float p[4][4];
#pragma unroll
      for (int mb = 0; mb < 4; ++mb) {
        f32x4 st = {};
        st = __builtin_amdgcn_mfma_f32_16x16x32_bf16(ak[mb][0], bq0, st, 0, 0, 0);
        st = __builtin_amdgcn_mfma_f32_16x16x32_bf16(ak[mb][1], bq1, st, 0, 0, 0);
#pragma unroll
        for (int r = 0; r < 4; ++r) p[mb][r] = __expf(st[r]);
      }

      // --- prefix/causal mask (only chunks that can contain invalid keys) ---
      if ((k0 + 64 > NP) && (k0 + 64 > qt + 1)) {
        int row = qt + c;
#pragma unroll
        for (int mb = 0; mb < 4; ++mb)
#pragma unroll
          for (int r = 0; r < 4; ++r) {
            int key = k0 + mb * 16 + (quad << 2) + r;
            bool v = (row < NP) ? (key < NP) : (key <= row);
            p[mb][r] = v ? p[mb][r] : 0.0f;
          }
      }
      float ls = 0.0f;
#pragma unroll
      for (int mb = 0; mb < 4; ++mb)
#pragma unroll
        for (int r = 0; r < 4; ++r) ls += p[mb][r];
      if (s) l1 += ls; else l0 += ls;

      // --- per 32-key half: transpose to B-frag (R3-verified), then PV ---
#pragma unroll
      for (int hh = 0; hh < 2; ++hh) {
        float* pa = p[2 * hh];      // keys k0+32hh+{4quad'+r}
        float* pb = p[2 * hh + 1];  // keys k0+32hh+16+{4quad'+r}
        uint32_t e0 = pack2bf(pa[0], pa[1]);
        uint32_t e1 = pack2bf(pa[2], pa[3]);
        uint32_t e2 = pack2bf(pb[0], pb[1]);
        uint32_t e3 = pack2bf(pb[2], pb[3]);
        uint32_t a0 = (uint32_t)__shfl((int)e0, L0);
        uint32_t b0 = (uint32_t)__shfl((int)e1, L0);
        uint32_t a1 = (uint32_t)__shfl((int)e0, L0 + 16);
        uint32_t b1 = (uint32_t)__shfl((int)e1, L0 + 16);
        uint32_t c0 = (uint32_t)__shfl((int)e2, L0);
        uint32_t d0 = (uint32_t)__shfl((int)e3, L0);
        uint32_t c1 = (uint32_t)__shfl((int)e2, L0 + 16);
        uint32_t d1 = (uint32_t)__shfl((int)e3, L0 + 16);
        union { uint32_t u[4]; bf16x8 v; } bp;
        bp.u[0] = hilo ? c0 : a0;
        bp.u[1] = hilo ? d0 : b0;
        bp.u[2] = hilo ? c1 : a1;
        bp.u[3] = hilo ? d1 : b1;
#pragma unroll
        for (int db = 0; db < 4; ++db)
          acc[db] = __builtin_amdgcn_mfma_f32_16x16x32_bf16(av[db][hh], bp.v, acc[db], 0, 0, 0);
      }
    }
    __syncthreads();                // protect LDS before next stage
  }

  // --- finalize both subtiles: quad-reduce l, normalize, 8B stores ---
#pragma unroll
  for (int s = 0; s < 2; ++s) {
    float l = s ? l1 : l0;
    f32x4* acc = s ? acc1 : acc0;
    int qt = s ? qt1 : qt0;
    l += __shfl_xor(l, 16);
    l += __shfl_xor(l, 32);
    float inv = 1.0f / l;
    size_t rowbase = ((size_t)(b * 512 + qt + c)) * 1024 + h * 64 + (quad << 2);
#pragma unroll
    for (int db = 0; db < 4; ++db) {
      s16x4 o;
#pragma unroll
      for (int r = 0; r < 4; ++r) o[r] = f2bf(acc[db][r] * inv);
      *(s16x4*)&ctx[rowbase + db * 16] = o;
    }
  }
}

// ---------------------------------------------------------------------------
// Output projection v4: v3 tiling (64m x 128n, BK=64, 512 blocks) + the same
// raw-barrier double-buffer pipeline as gemm_qkv v4. 6 async16 per wave per
// iter -> s_waitcnt vmcnt(6); 16 iterations; LDS 48 KB (2 blocks/CU = 96 OK).
// ---------------------------------------------------------------------------
__global__ __launch_bounds__(256, 2) void gemm_out(const short* __restrict__ ws,
                                                   const float* __restrict__ bias,
                                                   float* __restrict__ out) {
  __shared__ __align__(16) short As[2][4096];   // 64 rows x 64 k  = 8 chunks
  __shared__ __align__(16) short Bs[2][8192];   // 128 rows x 64 k = 16 chunks
  int bx = blockIdx.x;              // 0..511
  int mt = bx >> 3, nt = bx & 7;
  int m0 = mt << 6, n0 = nt << 7;
  const short* A  = ws + OFF_CT;
  const short* Bw = ws + OFF_WO;
  int t = threadIdx.x, lane = t & 63, wvi = t >> 6;
  int c = lane & 15, quad = lane >> 4;
  int wm = wvi >> 1, wn = wvi & 1;   // wave tile 32m x 64n
  f32x4 acc[2][4] = {};

  auto stage = [&](int buf, int kk) {   // 6 async16 per wave
#pragma unroll
    for (int i = 0; i < 6; ++i) {
      int ch = wvi * 6 + i;
      if (ch < 8) {
        int mg = ch >> 1, kh = ch & 1;
        async16(&As[buf][ch << 9], A + (m0 + mg * 16 + c) * 1024 + kk + kh * 32 + (quad << 3));
      } else {
        int cb = ch - 8, mg = cb >> 1, kh = cb & 1;
        async16(&Bs[buf][cb << 9], Bw + (n0 + mg * 16 + c) * 1024 + kk + kh * 32 + (quad << 3));
      }
    }
  };

  stage(0, 0);
  for (int it = 0; it < 16; ++it) {
    int buf = it & 1;
    if (it < 15) {
      stage(buf ^ 1, (it + 1) * 64);
      asm volatile("s_waitcnt vmcnt(6)" ::: "memory");
    } else {
      asm volatile("s_waitcnt vmcnt(0)" ::: "memory");
    }
    barrier_raw();

    bf16x8 af[2][2], bfr[4][2];
#pragma unroll
    for (int i = 0; i < 2; ++i)
#pragma unroll
      for (int kh = 0; kh < 2; ++kh)
        af[i][kh] = *(const bf16x8*)&As[buf][((((wm * 2 + i) << 1) + kh) << 9) + lane * 8];
#pragma unroll
    for (int j = 0; j < 4; ++j)
#pragma unroll
      for (int kh = 0; kh < 2; ++kh)
        bfr[j][kh] = *(const bf16x8*)&Bs[buf][((((wn * 4 + j) << 1) + kh) << 9) + lane * 8];
#pragma unroll
    for (int kh = 0; kh < 2; ++kh)
#pragma unroll
      for (int i = 0; i < 2; ++i)
#pragma unroll
        for (int j = 0; j < 4; ++j)
          acc[i][j] = __builtin_amdgcn_mfma_f32_16x16x32_bf16(af[i][kh], bfr[j][kh], acc[i][j], 0, 0, 0);
    barrier_raw();
  }

#pragma unroll
  for (int j = 0; j < 4; ++j) {
    int n = n0 + wn * 64 + j * 16 + c;
    float bj = bias[n];
#pragma unroll
    for (int i = 0; i < 2; ++i) {
      int mq = m0 + wm * 32 + i * 16 + quad * 4;
#pragma unroll
      for (int r = 0; r < 4; ++r)
        out[(size_t)(mq + r) * 1024 + n] = acc[i][j][r] + bj;
    }
  }
}

extern "C" void kernel_launch(void* const* d_in, const int* in_sizes, int n_in,
                              void* d_out, int out_size, void* d_ws, size_t ws_size,
                              hipStream_t stream) {
  (void)in_sizes; (void)n_in; (void)out_size; (void)ws_size;  // needs 48 MB of d_ws
  const float* x  = (const float*)d_in[0];
  const float* wq = (const float*)d_in[1];
  const float* wk = (const float*)d_in[2];
  const float* wv = (const float*)d_in[3];
  const float* wo = (const float*)d_in[4];
  const float* bo = (const float*)d_in[5];
  short* ws = (short*)d_ws;
  float* out = (float*)d_out;

  cvt5<<<8192, 256, 0, stream>>>(x, wq, wk, wv, wo, ws);
  gemm_qkv<<<768, 256, 0, stream>>>(ws);
  attn<<<512, 256, 0, stream>>>(ws);
  gemm_out<<<512, 256, 0, stream>>>(ws, bo, out);
}

// Round 9
// 156.521 us; speedup vs baseline: 1.2462x; 1.1644x over previous
//
#include <hip/hip_runtime.h>
#include <stdint.h>
#include <math.h>

// Problem constants
#define NB_B 8
#define NB_S 512
#define NB_D 1024
#define NB_H 16
#define NB_HD 64
#define NP 196            // image patches: bidirectional prefix block
#define MTOT 4096         // B*S

// Workspace layout (offsets in bf16/short elements). Total 48 MB.
// ALL matrices that feed async16 staging are stored CHUNK-SWIZZLED:
//   chunk (g = 16-row group, kb = 32-col block) = 512 shorts, laid out
//   [lane=quad*16+c][8 shorts], lane c = row%16, quad = (col%32)/8.
//   => async16 reads are contiguous 1KB bursts (16B/lane), the coalescing
//   sweet spot, instead of 16 scattered 64B segments (R9 theory).
#define OFF_XB 0          // x bf16 swizzled:      [g 0..255][kb 0..31][64][8]
#define OFF_WQ 4194304    // w swizzled (each):    [gn 0..63][kb 0..31][64][8]
#define OFF_WK 5242880
#define OFF_WV 6291456
#define OFF_WO 7340032
#define OFF_Q  8388608    // Q normal [B,H,S,hd] (read per-lane, not staged)
#define OFF_K  12582912   // K swizzled: [bh][kg 0..31][dblk 0..1][64][8]
#define OFF_VT 16777216   // V^T swizzled: [bh][dg 0..3][kblk 0..15][64][8]
#define OFF_CT 20971520   // ctx swizzled like XB: [g 0..255][kb 0..31][64][8]

typedef __attribute__((ext_vector_type(8))) short bf16x8;
typedef __attribute__((ext_vector_type(4))) float f32x4;
typedef __attribute__((ext_vector_type(4))) short s16x4;
typedef __attribute__((ext_vector_type(8))) short s16x8;

__device__ __forceinline__ short f2bf(float f) {
  union { float f; uint32_t u; } c; c.f = f;
  uint32_t r = (c.u + 0x7fffu + ((c.u >> 16) & 1u)) >> 16;   // RNE
  return (short)r;
}

// pack two fp32 -> one dword of two bf16 (round-half-up; softmax weights >=0)
__device__ __forceinline__ uint32_t pack2bf(float lo, float hi) {
  uint32_t ulo = __float_as_uint(lo) + 0x8000u;
  uint32_t uhi = __float_as_uint(hi) + 0x8000u;
  return __builtin_amdgcn_perm(uhi, ulo, 0x07060302u);  // [bf16(hi)|bf16(lo)]
}

__device__ __forceinline__ void async16(void* lds, const void* g) {
  // global -> LDS direct copy, 16B per lane; LDS dest = uniform base + lane*16
  __builtin_amdgcn_global_load_lds(
      (const __attribute__((address_space(1))) void*)g,
      (__attribute__((address_space(3))) void*)lds, 16, 0, 0);
}

// ---------------------------------------------------------------------------
// cvt5 v2: fp32 -> bf16 + CHUNK-SWIZZLE for x and the 4 weight matrices.
// 512 blocks: b<256 -> x group g=b (16 rows); else weight wi, n-group gn.
// Each thread handles 8 lane-slots: contiguous 16B writes; reads are 32B
// granules (absorbed by L1/L2, one-pass). w_q gets the 0.125 scale folded in.
// ---------------------------------------------------------------------------
__global__ __launch_bounds__(256) void cvt5(const float* __restrict__ x,
                                            const float* __restrict__ wq,
                                            const float* __restrict__ wk,
                                            const float* __restrict__ wv,
                                            const float* __restrict__ wo,
                                            short* __restrict__ ws) {
  int b = blockIdx.x, t = threadIdx.x;
  const float* src; short* dst; float scale;
  if (b < 256) {
    src = x + b * 16384;            // rows b*16..b*16+15
    dst = ws + OFF_XB + b * 16384;  // g = b
    scale = 1.0f;
  } else {
    int wi = (b - 256) >> 6, gn = (b - 256) & 63;
    const float* wsrc[4] = {wq, wk, wv, wo};
    src = wsrc[wi] + gn * 16384;
    dst = ws + OFF_WQ + wi * 1048576 + gn * 16384;
    scale = (wi == 0) ? 0.125f : 1.0f;
  }
  // slots: s = kb*64 + lane (lane = quad*16 + c); element (row c, col kb*32+quad*8+j)
#pragma unroll
  for (int it = 0; it < 8; ++it) {
    int s = t + it * 256;
    int kb = s >> 6, l = s & 63, quad = l >> 4, cc = l & 15;
    const float* sp = src + cc * 1024 + kb * 32 + quad * 8;
    float4 v0 = *(const float4*)sp;
    float4 v1 = *(const float4*)(sp + 4);
    s16x8 o;
    o[0] = f2bf(v0.x * scale); o[1] = f2bf(v0.y * scale);
    o[2] = f2bf(v0.z * scale); o[3] = f2bf(v0.w * scale);
    o[4] = f2bf(v1.x * scale); o[5] = f2bf(v1.y * scale);
    o[6] = f2bf(v1.z * scale); o[7] = f2bf(v1.w * scale);
    *(s16x8*)(dst + s * 8) = o;
  }
}

// ---------------------------------------------------------------------------
// QKV projection (R4 structure, swizzled staging): 128x128 tile, BK=32,
// 768 blocks (3/CU), 4 waves x 64x64. Staging is now 4 contiguous-1KB
// async16 per wave per iter. Epilogue: Q -> normal [B,H,S,hd]; K -> K_sw;
// V -> V_sw (swizzled for attn's async16).
// ---------------------------------------------------------------------------
__global__ __launch_bounds__(256, 2) void gemm_qkv(short* __restrict__ ws) {
  __shared__ __align__(16) short As[4096];   // 8 chunks
  __shared__ __align__(16) short Bs[4096];
  int bx = blockIdx.x;              // 0..767
  int wsel = bx >> 8;               // 0=Q 1=K 2=V
  int tile = bx & 255;
  int mt = tile >> 3, nt = tile & 7;
  int m0 = mt << 7, n0 = nt << 7;
  const short* A  = ws + OFF_XB;
  const short* Bw = ws + OFF_WQ + wsel * 1048576;
  int t = threadIdx.x, lane = t & 63, wvi = t >> 6;
  int c = lane & 15, quad = lane >> 4;
  int wm = wvi >> 1, wn = wvi & 1;
  int g0 = mt << 3, gn0 = nt << 3;  // 16-row group bases
  f32x4 acc[4][4] = {};

  for (int kk = 0; kk < 1024; kk += 32) {
    int kb = kk >> 5;
#pragma unroll
    for (int i = 0; i < 2; ++i) {
      int ch = wvi * 2 + i;
      async16(&As[ch << 9], A  + ((g0  + ch) * 32 + kb) * 512 + lane * 8);
      async16(&Bs[ch << 9], Bw + ((gn0 + ch) * 32 + kb) * 512 + lane * 8);
    }
    __syncthreads();                // drains vmcnt for global_load_lds
    bf16x8 af[4], bfr[4];
#pragma unroll
    for (int i = 0; i < 4; ++i) af[i]  = *(const bf16x8*)&As[((wm * 4 + i) << 9) + lane * 8];
#pragma unroll
    for (int j = 0; j < 4; ++j) bfr[j] = *(const bf16x8*)&Bs[((wn * 4 + j) << 9) + lane * 8];
#pragma unroll
    for (int i = 0; i < 4; ++i)
#pragma unroll
      for (int j = 0; j < 4; ++j)
        acc[i][j] = __builtin_amdgcn_mfma_f32_16x16x32_bf16(af[i], bfr[j], acc[i][j], 0, 0, 0);
    __syncthreads();                // protect LDS before next stage
  }

#pragma unroll
  for (int i = 0; i < 4; ++i) {
#pragma unroll
    for (int j = 0; j < 4; ++j) {
      int n = n0 + wn * 64 + j * 16 + c;        // output feature
      int h = n >> 6, d = n & 63;
      int mq = m0 + wm * 64 + i * 16 + quad * 4; // first of the 4 rows (reg dim)
      int bb = mq >> 9, srow = mq & 511;
      if (wsel == 0) {
        // Q normal [B,H,S,hd]
        short* outp = ws + OFF_Q;
#pragma unroll
        for (int r = 0; r < 4; ++r)
          outp[((bb * 16 + h) * 512 + srow + r) * 64 + d] = f2bf(acc[i][j][r]);
      } else if (wsel == 1) {
        // K_sw: [bh][kg][dblk][lane=qk*16+(row%16)][jd]; row%16 = quad*4+r
        int dblk = d >> 5, qk = (d >> 3) & 3, jd = d & 7;
        int kg = srow >> 4;
        size_t base = (size_t)(bb * 16 + h) * 32768 +
                      (size_t)(((kg * 2 + dblk) * 64 + qk * 16 + quad * 4)) * 8 + jd;
        short* outp = ws + OFF_K;
#pragma unroll
        for (int r = 0; r < 4; ++r) outp[base + r * 8] = f2bf(acc[i][j][r]);
      } else {
        // V_sw: [bh][dg][kblk][lane=qv*16+(d%16)][jv]; keys srow..srow+3
        int dg = d >> 4, cv = d & 15;
        int kblk = srow >> 5, qv = (srow >> 3) & 3, jv = srow & 7;  // jv=(quad&1)*4
        s16x4 o;
#pragma unroll
        for (int r = 0; r < 4; ++r) o[r] = f2bf(acc[i][j][r]);
        *(s16x4*)&ws[OFF_VT + (size_t)(bb * 16 + h) * 32768 +
                     (size_t)((dg * 16 + kblk) * 64 + qv * 16 + cv) * 8 + jv] = o;
      }
    }
  }
}

// ---------------------------------------------------------------------------
// Attention (R4 structure, swizzled K/V staging + swizzled CT output).
// ---------------------------------------------------------------------------
__global__ __launch_bounds__(256, 2) void attn(short* __restrict__ ws) {
  __shared__ __align__(16) short Kb[4096];   // 8 chunks: [key16 rel][d-half]
  __shared__ __align__(16) short Vb[4096];   // 8 chunks: [d16][key32-half]
  int bi = blockIdx.x;              // 0..511
  int bh = bi >> 2, qcr = bi & 3;
  int qc = (qcr + bh + 2 * (bh >> 6)) & 3;   // rotate so CU pairs mix light/heavy
  int t = threadIdx.x, lane = t & 63, wvi = t >> 6;
  int c = lane & 15, quad = lane >> 4;
  const short* Qh   = ws + OFF_Q  + bh * (512 * 64);
  const short* Ksw  = ws + OFF_K  + (size_t)bh * 32768;
  const short* Vsw  = ws + OFF_VT + (size_t)bh * 32768;
  short* ct = ws + OFF_CT;
  int b = bh >> 4, h = bh & 15;

  int qt0 = qc * 128 + wvi * 32;    // two 16-row subtiles per wave
  int qt1 = qt0 + 16;
  int kn0 = (qt0 + 16 > NP) ? (qt0 + 16) : NP;
  int kn1 = (qt1 + 16 > NP) ? (qt1 + 16) : NP;
  int knb = (qc * 128 + 128 > NP) ? (qc * 128 + 128) : NP;
  int NCH = (knb + 63) >> 6;        // 64-key chunks staged by the block

  // Q^T B-frags for both subtiles: [n=q=lane&15][k=d=quad*8+j] (+32 frag 1)
  bf16x8 q00 = *(const bf16x8*)(Qh + (qt0 + c) * 64 + (quad << 3));
  bf16x8 q01 = *(const bf16x8*)(Qh + (qt0 + c) * 64 + 32 + (quad << 3));
  bf16x8 q10 = *(const bf16x8*)(Qh + (qt1 + c) * 64 + (quad << 3));
  bf16x8 q11 = *(const bf16x8*)(Qh + (qt1 + c) * 64 + 32 + (quad << 3));

  f32x4 acc0[4] = {}, acc1[4] = {}; // ctx^T accumulators per subtile
  float l0 = 0.0f, l1 = 0.0f;       // in-lane softmax denominators
  int L0 = c + ((quad & 1) << 5);   // transpose source lane
  bool hilo = quad >= 2;

  for (int ch = 0; ch < NCH; ++ch) {
    int k0 = ch << 6;
    // --- stage: contiguous 1KB bursts from K_sw / V_sw ---
    {
      int kg = (k0 >> 4) + wvi;     // wave's 16-key group (K)
#pragma unroll
      for (int f = 0; f < 2; ++f)
        async16(&Kb[(wvi * 2 + f) << 9], Ksw + ((kg * 2 + f) * 512) + lane * 8);
      int kblk = k0 >> 5;           // wave's d-group = wvi (V)
#pragma unroll
      for (int f = 0; f < 2; ++f)
        async16(&Vb[(wvi * 2 + f) << 9], Vsw + ((wvi * 16 + kblk + f) * 512) + lane * 8);
    }
    __syncthreads();                // drains vmcnt for global_load_lds

    // K A-frags [m=key16][k=d] and V^T A-frags [m=d16][k=key32+..]
    bf16x8 ak[4][2], av[4][2];
#pragma unroll
    for (int mb = 0; mb < 4; ++mb)
#pragma unroll
      for (int f = 0; f < 2; ++f) {
        ak[mb][f] = *(const bf16x8*)&Kb[((mb * 2 + f) << 9) + lane * 8];
        av[mb][f] = *(const bf16x8*)&Vb[((mb * 2 + f) << 9) + lane * 8];
      }

#pragma unroll
    for (int s = 0; s < 2; ++s) {
      int qt = s ? qt1 : qt0;
      int kn = s ? kn1 : kn0;
      if (k0 >= kn) continue;       // subtile finished (other subtile may not be)
      bf16x8 bq0 = s ? q10 : q00;
      bf16x8 bq1 = s ? q11 : q01;
      f32x4* acc = s ? acc1 : acc0;

      // --- S^T = K . Q^T : 4 m-blocks of 16 keys ---
      float p[4][4];
#pragma unroll
      for (int mb = 0; mb < 4; ++mb) {
        f32x4 st = {};
        st = __builtin_amdgcn_mfma_f32_16x16x32_bf16(ak[mb][0], bq0, st, 0, 0, 0);
        st = __builtin_amdgcn_mfma_f32_16x16x32_bf16(ak[mb][1], bq1, st, 0, 0, 0);
#pragma unroll
        for (int r = 0; r < 4; ++r) p[mb][r] = __expf(st[r]);
      }

      // --- prefix/causal mask (only chunks that can contain invalid keys) ---
      if ((k0 + 64 > NP) && (k0 + 64 > qt + 1)) {
        int row = qt + c;
#pragma unroll
        for (int mb = 0; mb < 4; ++mb)
#pragma unroll
          for (int r = 0; r < 4; ++r) {
            int key = k0 + mb * 16 + (quad << 2) + r;
            bool v = (row < NP) ? (key < NP) : (key <= row);
            p[mb][r] = v ? p[mb][r] : 0.0f;
          }
      }
      float ls = 0.0f;
#pragma unroll
      for (int mb = 0; mb < 4; ++mb)
#pragma unroll
        for (int r = 0; r < 4; ++r) ls += p[mb][r];
      if (s) l1 += ls; else l0 += ls;

      // --- per 32-key half: transpose to B-frag (R3-verified), then PV ---
#pragma unroll
      for (int hh = 0; hh < 2; ++hh) {
        float* pa = p[2 * hh];      // keys k0+32hh+{4quad'+r}
        float* pb = p[2 * hh + 1];  // keys k0+32hh+16+{4quad'+r}
        uint32_t e0 = pack2bf(pa[0], pa[1]);
        uint32_t e1 = pack2bf(pa[2], pa[3]);
        uint32_t e2 = pack2bf(pb[0], pb[1]);
        uint32_t e3 = pack2bf(pb[2], pb[3]);
        uint32_t a0 = (uint32_t)__shfl((int)e0, L0);
        uint32_t b0 = (uint32_t)__shfl((int)e1, L0);
        uint32_t a1 = (uint32_t)__shfl((int)e0, L0 + 16);
        uint32_t b1 = (uint32_t)__shfl((int)e1, L0 + 16);
        uint32_t c0 = (uint32_t)__shfl((int)e2, L0);
        uint32_t d0 = (uint32_t)__shfl((int)e3, L0);
        uint32_t c1 = (uint32_t)__shfl((int)e2, L0 + 16);
        uint32_t d1 = (uint32_t)__shfl((int)e3, L0 + 16);
        union { uint32_t u[4]; bf16x8 v; } bp;
        bp.u[0] = hilo ? c0 : a0;
        bp.u[1] = hilo ? d0 : b0;
        bp.u[2] = hilo ? c1 : a1;
        bp.u[3] = hilo ? d1 : b1;
#pragma unroll
        for (int db = 0; db < 4; ++db)
          acc[db] = __builtin_amdgcn_mfma_f32_16x16x32_bf16(av[db][hh], bp.v, acc[db], 0, 0, 0);
      }
    }
    __syncthreads();                // protect LDS before next stage
  }

  // --- finalize: quad-reduce l, normalize, store ctx SWIZZLED (CT_sw) ---
#pragma unroll
  for (int s = 0; s < 2; ++s) {
    float l = s ? l1 : l0;
    f32x4* acc = s ? acc1 : acc0;
    int qt = s ? qt1 : qt0;
    l += __shfl_xor(l, 16);
    l += __shfl_xor(l, 32);
    float inv = 1.0f / l;
    int g = (b * 512 + qt) >> 4;    // 16-row group (qt multiple of 16)
#pragma unroll
    for (int db = 0; db < 4; ++db) {
      int col0 = h * 64 + db * 16 + quad * 4;   // first of 4 cols (r-run)
      int kb = col0 >> 5, qp = (col0 & 31) >> 3, jo = col0 & 7;
      s16x4 o;
#pragma unroll
      for (int r = 0; r < 4; ++r) o[r] = f2bf(acc[db][r] * inv);
      *(s16x4*)&ct[(size_t)((g * 32 + kb) * 64 + qp * 16 + c) * 8 + jo] = o;
    }
  }
}

// ---------------------------------------------------------------------------
// Output projection (R7-v3 structure, swizzled staging): 64m x 128n, BK=64,
// 512 blocks. A = CT_sw, B = WO_sw; 6 contiguous-1KB async16 per wave/iter.
// ---------------------------------------------------------------------------
__global__ __launch_bounds__(256, 2) void gemm_out(const short* __restrict__ ws,
                                                   const float* __restrict__ bias,
                                                   float* __restrict__ out) {
  __shared__ __align__(16) short As[4096];   // 8 chunks
  __shared__ __align__(16) short Bs[8192];   // 16 chunks
  int bx = blockIdx.x;              // 0..511
  int mt = bx >> 3, nt = bx & 7;
  int m0 = mt << 6, n0 = nt << 7;
  const short* A  = ws + OFF_CT;
  const short* Bw = ws + OFF_WO;
  int t = threadIdx.x, lane = t & 63, wvi = t >> 6;
  int c = lane & 15, quad = lane >> 4;
  int wm = wvi >> 1, wn = wvi & 1;   // wave tile 32m x 64n
  int g0 = m0 >> 4, gn0 = n0 >> 4;
  f32x4 acc[2][4] = {};

  for (int kk = 0; kk < 1024; kk += 64) {
    int kb = kk >> 5;
#pragma unroll
    for (int i = 0; i < 6; ++i) {
      int ch = wvi * 6 + i;
      if (ch < 8) {
        int mg = ch >> 1, kh = ch & 1;
        async16(&As[ch << 9], A + ((g0 + mg) * 32 + kb + kh) * 512 + lane * 8);
      } else {
        int cb = ch - 8, mg = cb >> 1, kh = cb & 1;
        async16(&Bs[cb << 9], Bw + ((gn0 + mg) * 32 + kb + kh) * 512 + lane * 8);
      }
    }
    __syncthreads();                // drains vmcnt for global_load_lds

    bf16x8 af[2][2], bfr[4][2];
#pragma unroll
    for (int i = 0; i < 2; ++i)
#pragma unroll
      for (int kh = 0; kh < 2; ++kh)
        af[i][kh] = *(const bf16x8*)&As[((((wm * 2 + i) << 1) + kh) << 9) + lane * 8];
#pragma unroll
    for (int j = 0; j < 4; ++j)
#pragma unroll
      for (int kh = 0; kh < 2; ++kh)
        bfr[j][kh] = *(const bf16x8*)&Bs[((((wn * 4 + j) << 1) + kh) << 9) + lane * 8];
#pragma unroll
    for (int kh = 0; kh < 2; ++kh)
#pragma unroll
      for (int i = 0; i < 2; ++i)
#pragma unroll
        for (int j = 0; j < 4; ++j)
          acc[i][j] = __builtin_amdgcn_mfma_f32_16x16x32_bf16(af[i][kh], bfr[j][kh], acc[i][j], 0, 0, 0);
    __syncthreads();                // protect LDS before next stage
  }

#pragma unroll
  for (int j = 0; j < 4; ++j) {
    int n = n0 + wn * 64 + j * 16 + c;
    float bj = bias[n];
#pragma unroll
    for (int i = 0; i < 2; ++i) {
      int mq = m0 + wm * 32 + i * 16 + quad * 4;
#pragma unroll
      for (int r = 0; r < 4; ++r)
        out[(size_t)(mq + r) * 1024 + n] = acc[i][j][r] + bj;
    }
  }
}

extern "C" void kernel_launch(void* const* d_in, const int* in_sizes, int n_in,
                              void* d_out, int out_size, void* d_ws, size_t ws_size,
                              hipStream_t stream) {
  (void)in_sizes; (void)n_in; (void)out_size; (void)ws_size;  // needs 48 MB of d_ws
  const float* x  = (const float*)d_in[0];
  const float* wq = (const float*)d_in[1];
  const float* wk = (const float*)d_in[2];
  const float* wv = (const float*)d_in[3];
  const float* wo = (const float*)d_in[4];
  const float* bo = (const float*)d_in[5];
  short* ws = (short*)d_ws;
  float* out = (float*)d_out;

  cvt5<<<512, 256, 0, stream>>>(x, wq, wk, wv, wo, ws);
  gemm_qkv<<<768, 256, 0, stream>>>(ws);
  attn<<<512, 256, 0, stream>>>(ws);
  gemm_out<<<512, 256, 0, stream>>>(ws, bo, out);
}

// Round 10
// 153.720 us; speedup vs baseline: 1.2689x; 1.0182x over previous
//
#include <hip/hip_runtime.h>
#include <stdint.h>
#include <math.h>

// Problem constants
#define NB_B 8
#define NB_S 512
#define NB_D 1024
#define NB_H 16
#define NB_HD 64
#define NP 196            // image patches: bidirectional prefix block
#define MTOT 4096         // B*S

// Workspace layout (offsets in bf16/short elements). Total 48 MB.
// ALL matrices that feed async16 staging (or wave-frag loads) are stored
// CHUNK-SWIZZLED: chunk (g = 16-row group, kb = 32-col block) = 512 shorts,
// [lane=quad*16+c][8 shorts], c = row%16, quad = (col%32)/8.
// => async16/frag reads are contiguous 1KB wave bursts (R9-verified win).
#define OFF_XB 0          // x bf16 swizzled:      [g 0..255][kb 0..31][64][8]
#define OFF_WQ 4194304    // w swizzled (each):    [gn 0..63][kb 0..31][64][8]
#define OFF_WK 5242880
#define OFF_WV 6291456
#define OFF_WO 7340032
#define OFF_Q  8388608    // Q swizzled: [bh][qg 0..31][dblk 0..1][64][8]  (R10)
#define OFF_K  12582912   // K swizzled: [bh][kg 0..31][dblk 0..1][64][8]
#define OFF_VT 16777216   // V^T swizzled: [bh][dg 0..3][kblk 0..15][64][8]
#define OFF_CT 20971520   // ctx swizzled like XB: [g 0..255][kb 0..31][64][8]

typedef __attribute__((ext_vector_type(8))) short bf16x8;
typedef __attribute__((ext_vector_type(4))) float f32x4;
typedef __attribute__((ext_vector_type(4))) short s16x4;
typedef __attribute__((ext_vector_type(8))) short s16x8;

__device__ __forceinline__ short f2bf(float f) {
  union { float f; uint32_t u; } c; c.f = f;
  uint32_t r = (c.u + 0x7fffu + ((c.u >> 16) & 1u)) >> 16;   // RNE
  return (short)r;
}

// pack two fp32 -> one dword of two bf16 (round-half-up; softmax weights >=0)
__device__ __forceinline__ uint32_t pack2bf(float lo, float hi) {
  uint32_t ulo = __float_as_uint(lo) + 0x8000u;
  uint32_t uhi = __float_as_uint(hi) + 0x8000u;
  return __builtin_amdgcn_perm(uhi, ulo, 0x07060302u);  // [bf16(hi)|bf16(lo)]
}

__device__ __forceinline__ void async16(void* lds, const void* g) {
  // global -> LDS direct copy, 16B per lane; LDS dest = uniform base + lane*16
  __builtin_amdgcn_global_load_lds(
      (const __attribute__((address_space(1))) void*)g,
      (__attribute__((address_space(3))) void*)lds, 16, 0, 0);
}

// ---------------------------------------------------------------------------
// cvt5 v3 (R10): fp32 -> bf16 + chunk-swizzle via LDS transpose.
//   R9's cvt5 had scattered 32B reads (16 lanes x 4KB apart). Now:
//   phase 1: fully-coalesced float4 reads, bf16-pack into LDS rows
//            (stride 513 dwords -> phase-2 reads conflict-free);
//   phase 2: each thread reads its chunk-slot (4 dwords) from LDS and does
//            ONE contiguous 16B global write (1KB/wave bursts).
//   512 blocks: b<256 -> x group g=b; else weight wi = (b-256)/64, gn.
// ---------------------------------------------------------------------------
__global__ __launch_bounds__(256) void cvt5(const float* __restrict__ x,
                                            const float* __restrict__ wq,
                                            const float* __restrict__ wk,
                                            const float* __restrict__ wv,
                                            const float* __restrict__ wo,
                                            short* __restrict__ ws) {
  __shared__ uint32_t lt[16 * 513];   // 16 rows x 513 dwords (1026 shorts, +2 pad)
  int b = blockIdx.x, t = threadIdx.x;
  const float* src; short* dst; float scale;
  if (b < 256) {
    src = x + b * 16384;            // rows b*16 .. b*16+15
    dst = ws + OFF_XB + b * 16384;
    scale = 1.0f;
  } else {
    int wi = (b - 256) >> 6, gn = (b - 256) & 63;
    switch (wi) {
      case 0:  src = wq + gn * 16384; scale = 0.125f; break;
      case 1:  src = wk + gn * 16384; scale = 1.0f;   break;
      case 2:  src = wv + gn * 16384; scale = 1.0f;   break;
      default: src = wo + gn * 16384; scale = 1.0f;   break;
    }
    dst = ws + OFF_WQ + wi * 1048576 + gn * 16384;
  }
  // --- phase 1: coalesced float4 reads -> packed bf16 pairs in LDS ---
#pragma unroll
  for (int i = 0; i < 16; ++i) {
    int flat = t + i * 256;          // float4 id, 0..4095
    int row = flat >> 8, col4 = flat & 255;
    float4 v = *(const float4*)(src + flat * 4);
    uint32_t lo = (uint32_t)(uint16_t)f2bf(v.x * scale) |
                  ((uint32_t)(uint16_t)f2bf(v.y * scale) << 16);
    uint32_t hi = (uint32_t)(uint16_t)f2bf(v.z * scale) |
                  ((uint32_t)(uint16_t)f2bf(v.w * scale) << 16);
    lt[row * 513 + col4 * 2]     = lo;
    lt[row * 513 + col4 * 2 + 1] = hi;
  }
  __syncthreads();
  // --- phase 2: swizzled LDS gather -> contiguous 16B global writes ---
#pragma unroll
  for (int i = 0; i < 8; ++i) {
    int s = t + i * 256;             // chunk-slot id, 0..2047
    int kb = s >> 6, l = s & 63, quad = l >> 4, cc = l & 15;
    int base = cc * 513 + kb * 16 + quad * 4;
    union { uint32_t u[4]; s16x8 v; } o;
    o.u[0] = lt[base];     o.u[1] = lt[base + 1];
    o.u[2] = lt[base + 2]; o.u[3] = lt[base + 3];
    *(s16x8*)(dst + s * 8) = o.v;
  }
}

// ---------------------------------------------------------------------------
// QKV projection (R9 structure): 128x128 tile, BK=32, 768 blocks, swizzled
// 1KB-burst staging. Epilogue: Q AND K -> chunk-swizzled [bh][g][dblk][64][8]
// (identical formula, different base); V -> V_sw.
// ---------------------------------------------------------------------------
__global__ __launch_bounds__(256, 2) void gemm_qkv(short* __restrict__ ws) {
  __shared__ __align__(16) short As[4096];   // 8 chunks
  __shared__ __align__(16) short Bs[4096];
  int bx = blockIdx.x;              // 0..767
  int wsel = bx >> 8;               // 0=Q 1=K 2=V
  int tile = bx & 255;
  int mt = tile >> 3, nt = tile & 7;
  int m0 = mt << 7, n0 = nt << 7;
  const short* A  = ws + OFF_XB;
  const short* Bw = ws + OFF_WQ + wsel * 1048576;
  int t = threadIdx.x, lane = t & 63, wvi = t >> 6;
  int c = lane & 15, quad = lane >> 4;
  int wm = wvi >> 1, wn = wvi & 1;
  int g0 = mt << 3, gn0 = nt << 3;  // 16-row group bases
  f32x4 acc[4][4] = {};

  for (int kk = 0; kk < 1024; kk += 32) {
    int kb = kk >> 5;
#pragma unroll
    for (int i = 0; i < 2; ++i) {
      int ch = wvi * 2 + i;
      async16(&As[ch << 9], A  + ((g0  + ch) * 32 + kb) * 512 + lane * 8);
      async16(&Bs[ch << 9], Bw + ((gn0 + ch) * 32 + kb) * 512 + lane * 8);
    }
    __syncthreads();                // drains vmcnt for global_load_lds
    bf16x8 af[4], bfr[4];
#pragma unroll
    for (int i = 0; i < 4; ++i) af[i]  = *(const bf16x8*)&As[((wm * 4 + i) << 9) + lane * 8];
#pragma unroll
    for (int j = 0; j < 4; ++j) bfr[j] = *(const bf16x8*)&Bs[((wn * 4 + j) << 9) + lane * 8];
#pragma unroll
    for (int i = 0; i < 4; ++i)
#pragma unroll
      for (int j = 0; j < 4; ++j)
        acc[i][j] = __builtin_amdgcn_mfma_f32_16x16x32_bf16(af[i], bfr[j], acc[i][j], 0, 0, 0);
    __syncthreads();                // protect LDS before next stage
  }

#pragma unroll
  for (int i = 0; i < 4; ++i) {
#pragma unroll
    for (int j = 0; j < 4; ++j) {
      int n = n0 + wn * 64 + j * 16 + c;        // output feature
      int h = n >> 6, d = n & 63;
      int mq = m0 + wm * 64 + i * 16 + quad * 4; // first of the 4 rows (reg dim)
      int bb = mq >> 9, srow = mq & 511;
      if (wsel < 2) {
        // Q_sw / K_sw: [bh][g][dblk][lane=qk*16+(row%16)][jd]; row%16=quad*4+r
        int dblk = d >> 5, qk = (d >> 3) & 3, jd = d & 7;
        int g = srow >> 4;
        short* outp = ws + (wsel == 0 ? OFF_Q : OFF_K);
        size_t base = (size_t)(bb * 16 + h) * 32768 +
                      (size_t)(((g * 2 + dblk) * 64 + qk * 16 + quad * 4)) * 8 + jd;
#pragma unroll
        for (int r = 0; r < 4; ++r) outp[base + r * 8] = f2bf(acc[i][j][r]);
      } else {
        // V_sw: [bh][dg][kblk][lane=qv*16+(d%16)][jv]; keys srow..srow+3
        int dg = d >> 4, cv = d & 15;
        int kblk = srow >> 5, qv = (srow >> 3) & 3, jv = srow & 7;  // jv=(quad&1)*4
        s16x4 o;
#pragma unroll
        for (int r = 0; r < 4; ++r) o[r] = f2bf(acc[i][j][r]);
        *(s16x4*)&ws[OFF_VT + (size_t)(bb * 16 + h) * 32768 +
                     (size_t)((dg * 16 + kblk) * 64 + qv * 16 + cv) * 8 + jv] = o;
      }
    }
  }
}

// ---------------------------------------------------------------------------
// Attention (R9 structure; Q loads now coalesced from Q_sw).
// ---------------------------------------------------------------------------
__global__ __launch_bounds__(256, 2) void attn(short* __restrict__ ws) {
  __shared__ __align__(16) short Kb[4096];   // 8 chunks: [key16 rel][d-half]
  __shared__ __align__(16) short Vb[4096];   // 8 chunks: [d16][key32-half]
  int bi = blockIdx.x;              // 0..511
  int bh = bi >> 2, qcr = bi & 3;
  int qc = (qcr + bh + 2 * (bh >> 6)) & 3;   // rotate so CU pairs mix light/heavy
  int t = threadIdx.x, lane = t & 63, wvi = t >> 6;
  int c = lane & 15, quad = lane >> 4;
  const short* Qsw  = ws + OFF_Q  + (size_t)bh * 32768;
  const short* Ksw  = ws + OFF_K  + (size_t)bh * 32768;
  const short* Vsw  = ws + OFF_VT + (size_t)bh * 32768;
  short* ct = ws + OFF_CT;
  int b = bh >> 4, h = bh & 15;

  int qt0 = qc * 128 + wvi * 32;    // two 16-row subtiles per wave
  int qt1 = qt0 + 16;
  int kn0 = (qt0 + 16 > NP) ? (qt0 + 16) : NP;
  int kn1 = (qt1 + 16 > NP) ? (qt1 + 16) : NP;
  int knb = (qc * 128 + 128 > NP) ? (qc * 128 + 128) : NP;
  int NCH = (knb + 63) >> 6;        // 64-key chunks staged by the block

  // Q^T B-frags from Q_sw: chunk (qg, dblk) lane -> row qg*16+c, col dblk*32+quad*8+j
  int qg0 = qt0 >> 4, qg1 = qt1 >> 4;
  bf16x8 q00 = *(const bf16x8*)(Qsw + ((qg0 * 2 + 0) * 64 + lane) * 8);
  bf16x8 q01 = *(const bf16x8*)(Qsw + ((qg0 * 2 + 1) * 64 + lane) * 8);
  bf16x8 q10 = *(const bf16x8*)(Qsw + ((qg1 * 2 + 0) * 64 + lane) * 8);
  bf16x8 q11 = *(const bf16x8*)(Qsw + ((qg1 * 2 + 1) * 64 + lane) * 8);

  f32x4 acc0[4] = {}, acc1[4] = {}; // ctx^T accumulators per subtile
  float l0 = 0.0f, l1 = 0.0f;       // in-lane softmax denominators
  int L0 = c + ((quad & 1) << 5);   // transpose source lane
  bool hilo = quad >= 2;

  for (int ch = 0; ch < NCH; ++ch) {
    int k0 = ch << 6;
    // --- stage: contiguous 1KB bursts from K_sw / V_sw ---
    {
      int kg = (k0 >> 4) + wvi;     // wave's 16-key group (K)
#pragma unroll
      for (int f = 0; f < 2; ++f)
        async16(&Kb[(wvi * 2 + f) << 9], Ksw + ((kg * 2 + f) * 512) + lane * 8);
      int kblk = k0 >> 5;           // wave's d-group = wvi (V)
#pragma unroll
      for (int f = 0; f < 2; ++f)
        async16(&Vb[(wvi * 2 + f) << 9], Vsw + ((wvi * 16 + kblk + f) * 512) + lane * 8);
    }
    __syncthreads();                // drains vmcnt for global_load_lds

    // K A-frags [m=key16][k=d] and V^T A-frags [m=d16][k=key32+..]
    bf16x8 ak[4][2], av[4][2];
#pragma unroll
    for (int mb = 0; mb < 4; ++mb)
#pragma unroll
      for (int f = 0; f < 2; ++f) {
        ak[mb][f] = *(const bf16x8*)&Kb[((mb * 2 + f) << 9) + lane * 8];
        av[mb][f] = *(const bf16x8*)&Vb[((mb * 2 + f) << 9) + lane * 8];
      }

#pragma unroll
    for (int s = 0; s < 2; ++s) {
      int qt = s ? qt1 : qt0;
      int kn = s ? kn1 : kn0;
      if (k0 >= kn) continue;       // subtile finished (other subtile may not be)
      bf16x8 bq0 = s ? q10 : q00;
      bf16x8 bq1 = s ? q11 : q01;
      f32x4* acc = s ? acc1 : acc0;

      // --- S^T = K . Q^T : 4 m-blocks of 16 keys ---
      float p[4][4];
#pragma unroll
      for (int mb = 0; mb < 4; ++mb) {
        f32x4 st = {};
        st = __builtin_amdgcn_mfma_f32_16x16x32_bf16(ak[mb][0], bq0, st, 0, 0, 0);
        st = __builtin_amdgcn_mfma_f32_16x16x32_bf16(ak[mb][1], bq1, st, 0, 0, 0);
#pragma unroll
        for (int r = 0; r < 4; ++r) p[mb][r] = __expf(st[r]);
      }

      // --- prefix/causal mask (only chunks that can contain invalid keys) ---
      if ((k0 + 64 > NP) && (k0 + 64 > qt + 1)) {
        int row = qt + c;
#pragma unroll
        for (int mb = 0; mb < 4; ++mb)
#pragma unroll
          for (int r = 0; r < 4; ++r) {
            int key = k0 + mb * 16 + (quad << 2) + r;
            bool v = (row < NP) ? (key < NP) : (key <= row);
            p[mb][r] = v ? p[mb][r] : 0.0f;
          }
      }
      float ls = 0.0f;
#pragma unroll
      for (int mb = 0; mb < 4; ++mb)
#pragma unroll
        for (int r = 0; r < 4; ++r) ls += p[mb][r];
      if (s) l1 += ls; else l0 += ls;

      // --- per 32-key half: transpose to B-frag (R3-verified), then PV ---
#pragma unroll
      for (int hh = 0; hh < 2; ++hh) {
        float* pa = p[2 * hh];      // keys k0+32hh+{4quad'+r}
        float* pb = p[2 * hh + 1];  // keys k0+32hh+16+{4quad'+r}
        uint32_t e0 = pack2bf(pa[0], pa[1]);
        uint32_t e1 = pack2bf(pa[2], pa[3]);
        uint32_t e2 = pack2bf(pb[0], pb[1]);
        uint32_t e3 = pack2bf(pb[2], pb[3]);
        uint32_t a0 = (uint32_t)__shfl((int)e0, L0);
        uint32_t b0 = (uint32_t)__shfl((int)e1, L0);
        uint32_t a1 = (uint32_t)__shfl((int)e0, L0 + 16);
        uint32_t b1 = (uint32_t)__shfl((int)e1, L0 + 16);
        uint32_t c0 = (uint32_t)__shfl((int)e2, L0);
        uint32_t d0 = (uint32_t)__shfl((int)e3, L0);
        uint32_t c1 = (uint32_t)__shfl((int)e2, L0 + 16);
        uint32_t d1 = (uint32_t)__shfl((int)e3, L0 + 16);
        union { uint32_t u[4]; bf16x8 v; } bp;
        bp.u[0] = hilo ? c0 : a0;
        bp.u[1] = hilo ? d0 : b0;
        bp.u[2] = hilo ? c1 : a1;
        bp.u[3] = hilo ? d1 : b1;
#pragma unroll
        for (int db = 0; db < 4; ++db)
          acc[db] = __builtin_amdgcn_mfma_f32_16x16x32_bf16(av[db][hh], bp.v, acc[db], 0, 0, 0);
      }
    }
    __syncthreads();                // protect LDS before next stage
  }

  // --- finalize: quad-reduce l, normalize, store ctx SWIZZLED (CT_sw) ---
#pragma unroll
  for (int s = 0; s < 2; ++s) {
    float l = s ? l1 : l0;
    f32x4* acc = s ? acc1 : acc0;
    int qt = s ? qt1 : qt0;
    l += __shfl_xor(l, 16);
    l += __shfl_xor(l, 32);
    float inv = 1.0f / l;
    int g = (b * 512 + qt) >> 4;    // 16-row group (qt multiple of 16)
#pragma unroll
    for (int db = 0; db < 4; ++db) {
      int col0 = h * 64 + db * 16 + quad * 4;   // first of 4 cols (r-run)
      int kb = col0 >> 5, qp = (col0 & 31) >> 3, jo = col0 & 7;
      s16x4 o;
#pragma unroll
      for (int r = 0; r < 4; ++r) o[r] = f2bf(acc[db][r] * inv);
      *(s16x4*)&ct[(size_t)((g * 32 + kb) * 64 + qp * 16 + c) * 8 + jo] = o;
    }
  }
}

// ---------------------------------------------------------------------------
// Output projection (R9 structure): 64m x 128n, BK=64, 512 blocks, swizzled
// 1KB-burst staging from CT_sw / WO_sw.
// ---------------------------------------------------------------------------
__global__ __launch_bounds__(256, 2) void gemm_out(const short* __restrict__ ws,
                                                   const float* __restrict__ bias,
                                                   float* __restrict__ out) {
  __shared__ __align__(16) short As[4096];   // 8 chunks
  __shared__ __align__(16) short Bs[8192];   // 16 chunks
  int bx = blockIdx.x;              // 0..511
  int mt = bx >> 3, nt = bx & 7;
  int m0 = mt << 6, n0 = nt << 7;
  const short* A  = ws + OFF_CT;
  const short* Bw = ws + OFF_WO;
  int t = threadIdx.x, lane = t & 63, wvi = t >> 6;
  int c = lane & 15, quad = lane >> 4;
  int wm = wvi >> 1, wn = wvi & 1;   // wave tile 32m x 64n
  int g0 = m0 >> 4, gn0 = n0 >> 4;
  f32x4 acc[2][4] = {};

  for (int kk = 0; kk < 1024; kk += 64) {
    int kb = kk >> 5;
#pragma unroll
    for (int i = 0; i < 6; ++i) {
      int ch = wvi * 6 + i;
      if (ch < 8) {
        int mg = ch >> 1, kh = ch & 1;
        async16(&As[ch << 9], A + ((g0 + mg) * 32 + kb + kh) * 512 + lane * 8);
      } else {
        int cb = ch - 8, mg = cb >> 1, kh = cb & 1;
        async16(&Bs[cb << 9], Bw + ((gn0 + mg) * 32 + kb + kh) * 512 + lane * 8);
      }
    }
    __syncthreads();                // drains vmcnt for global_load_lds

    bf16x8 af[2][2], bfr[4][2];
#pragma unroll
    for (int i = 0; i < 2; ++i)
#pragma unroll
      for (int kh = 0; kh < 2; ++kh)
        af[i][kh] = *(const bf16x8*)&As[((((wm * 2 + i) << 1) + kh) << 9) + lane * 8];
#pragma unroll
    for (int j = 0; j < 4; ++j)
#pragma unroll
      for (int kh = 0; kh < 2; ++kh)
        bfr[j][kh] = *(const bf16x8*)&Bs[((((wn * 4 + j) << 1) + kh) << 9) + lane * 8];
#pragma unroll
    for (int kh = 0; kh < 2; ++kh)
#pragma unroll
      for (int i = 0; i < 2; ++i)
#pragma unroll
        for (int j = 0; j < 4; ++j)
          acc[i][j] = __builtin_amdgcn_mfma_f32_16x16x32_bf16(af[i][kh], bfr[j][kh], acc[i][j], 0, 0, 0);
    __syncthreads();                // protect LDS before next stage
  }

#pragma unroll
  for (int j = 0; j < 4; ++j) {
    int n = n0 + wn * 64 + j * 16 + c;
    float bj = bias[n];
#pragma unroll
    for (int i = 0; i < 2; ++i) {
      int mq = m0 + wm * 32 + i * 16 + quad * 4;
#pragma unroll
      for (int r = 0; r < 4; ++r)
        out[(size_t)(mq + r) * 1024 + n] = acc[i][j][r] + bj;
    }
  }
}

extern "C" void kernel_launch(void* const* d_in, const int* in_sizes, int n_in,
                              void* d_out, int out_size, void* d_ws, size_t ws_size,
                              hipStream_t stream) {
  (void)in_sizes; (void)n_in; (void)out_size; (void)ws_size;  // needs 48 MB of d_ws
  const float* x  = (const float*)d_in[0];
  const float* wq = (const float*)d_in[1];
  const float* wk = (const float*)d_in[2];
  const float* wv = (const float*)d_in[3];
  const float* wo = (const float*)d_in[4];
  const float* bo = (const float*)d_in[5];
  short* ws = (short*)d_ws;
  float* out = (float*)d_out;

  cvt5<<<512, 256, 0, stream>>>(x, wq, wk, wv, wo, ws);
  gemm_qkv<<<768, 256, 0, stream>>>(ws);
  attn<<<512, 256, 0, stream>>>(ws);
  gemm_out<<<512, 256, 0, stream>>>(ws, bo, out);
}

// Round 11
// 152.683 us; speedup vs baseline: 1.2775x; 1.0068x over previous
//
#include <hip/hip_runtime.h>
#include <stdint.h>
#include <math.h>

// Problem constants
#define NB_B 8
#define NB_S 512
#define NB_D 1024
#define NB_H 16
#define NB_HD 64
#define NP 196            // image patches: bidirectional prefix block
#define MTOT 4096         // B*S

// Workspace layout (offsets in bf16/short elements). Total 48 MB.
// ALL matrices that feed async16 staging (or wave-frag loads) are stored
// CHUNK-SWIZZLED: chunk (g = 16-row group, kb = 32-col block) = 512 shorts,
// [lane=quad*16+c][8 shorts], c = row%16, quad = (col%32)/8.
// => async16/frag reads are contiguous 1KB wave bursts (R9-verified win).
#define OFF_XB 0          // x bf16 swizzled:      [g 0..255][kb 0..31][64][8]
#define OFF_WQ 4194304    // w swizzled (each):    [gn 0..63][kb 0..31][64][8]
#define OFF_WK 5242880
#define OFF_WV 6291456
#define OFF_WO 7340032
#define OFF_Q  8388608    // Q swizzled: [bh][qg 0..31][dblk 0..1][64][8]
#define OFF_K  12582912   // K swizzled: [bh][kg 0..31][dblk 0..1][64][8]
#define OFF_VT 16777216   // V^T swizzled: [bh][dg 0..3][kblk 0..15][64][8]
#define OFF_CT 20971520   // ctx swizzled like XB: [g 0..255][kb 0..31][64][8]

typedef __attribute__((ext_vector_type(8))) short bf16x8;
typedef __attribute__((ext_vector_type(4))) float f32x4;
typedef __attribute__((ext_vector_type(4))) short s16x4;
typedef __attribute__((ext_vector_type(8))) short s16x8;

__device__ __forceinline__ short f2bf(float f) {
  union { float f; uint32_t u; } c; c.f = f;
  uint32_t r = (c.u + 0x7fffu + ((c.u >> 16) & 1u)) >> 16;   // RNE
  return (short)r;
}

// pack two fp32 -> one dword of two bf16 (round-half-up; softmax weights >=0)
__device__ __forceinline__ uint32_t pack2bf(float lo, float hi) {
  uint32_t ulo = __float_as_uint(lo) + 0x8000u;
  uint32_t uhi = __float_as_uint(hi) + 0x8000u;
  return __builtin_amdgcn_perm(uhi, ulo, 0x07060302u);  // [bf16(hi)|bf16(lo)]
}

__device__ __forceinline__ void async16(void* lds, const void* g) {
  // global -> LDS direct copy, 16B per lane; LDS dest = uniform base + lane*16
  __builtin_amdgcn_global_load_lds(
      (const __attribute__((address_space(1))) void*)g,
      (__attribute__((address_space(3))) void*)lds, 16, 0, 0);
}

// ---------------------------------------------------------------------------
// cvt5 v3: fp32 -> bf16 + chunk-swizzle via LDS transpose (R10-verified).
// ---------------------------------------------------------------------------
__global__ __launch_bounds__(256) void cvt5(const float* __restrict__ x,
                                            const float* __restrict__ wq,
                                            const float* __restrict__ wk,
                                            const float* __restrict__ wv,
                                            const float* __restrict__ wo,
                                            short* __restrict__ ws) {
  __shared__ uint32_t lt[16 * 513];   // 16 rows x 513 dwords (+pad: phase-2 conflict-free)
  int b = blockIdx.x, t = threadIdx.x;
  const float* src; short* dst; float scale;
  if (b < 256) {
    src = x + b * 16384;            // rows b*16 .. b*16+15
    dst = ws + OFF_XB + b * 16384;
    scale = 1.0f;
  } else {
    int wi = (b - 256) >> 6, gn = (b - 256) & 63;
    switch (wi) {
      case 0:  src = wq + gn * 16384; scale = 0.125f; break;
      case 1:  src = wk + gn * 16384; scale = 1.0f;   break;
      case 2:  src = wv + gn * 16384; scale = 1.0f;   break;
      default: src = wo + gn * 16384; scale = 1.0f;   break;
    }
    dst = ws + OFF_WQ + wi * 1048576 + gn * 16384;
  }
  // --- phase 1: coalesced float4 reads -> packed bf16 pairs in LDS ---
#pragma unroll
  for (int i = 0; i < 16; ++i) {
    int flat = t + i * 256;          // float4 id, 0..4095
    int row = flat >> 8, col4 = flat & 255;
    float4 v = *(const float4*)(src + flat * 4);
    uint32_t lo = (uint32_t)(uint16_t)f2bf(v.x * scale) |
                  ((uint32_t)(uint16_t)f2bf(v.y * scale) << 16);
    uint32_t hi = (uint32_t)(uint16_t)f2bf(v.z * scale) |
                  ((uint32_t)(uint16_t)f2bf(v.w * scale) << 16);
    lt[row * 513 + col4 * 2]     = lo;
    lt[row * 513 + col4 * 2 + 1] = hi;
  }
  __syncthreads();
  // --- phase 2: swizzled LDS gather -> contiguous 16B global writes ---
#pragma unroll
  for (int i = 0; i < 8; ++i) {
    int s = t + i * 256;             // chunk-slot id, 0..2047
    int kb = s >> 6, l = s & 63, quad = l >> 4, cc = l & 15;
    int base = cc * 513 + kb * 16 + quad * 4;
    union { uint32_t u[4]; s16x8 v; } o;
    o.u[0] = lt[base];     o.u[1] = lt[base + 1];
    o.u[2] = lt[base + 2]; o.u[3] = lt[base + 3];
    *(s16x8*)(dst + s * 8) = o.v;
  }
}

// ---------------------------------------------------------------------------
// QKV projection (R9/R10 structure, unchanged): 128x128 tile, BK=32, 768
// blocks, swizzled 1KB-burst staging. Epilogue: Q,K -> chunk-swizzled;
// V -> V_sw.
// ---------------------------------------------------------------------------
__global__ __launch_bounds__(256, 2) void gemm_qkv(short* __restrict__ ws) {
  __shared__ __align__(16) short As[4096];   // 8 chunks
  __shared__ __align__(16) short Bs[4096];
  int bx = blockIdx.x;              // 0..767
  int wsel = bx >> 8;               // 0=Q 1=K 2=V
  int tile = bx & 255;
  int mt = tile >> 3, nt = tile & 7;
  int m0 = mt << 7, n0 = nt << 7;
  const short* A  = ws + OFF_XB;
  const short* Bw = ws + OFF_WQ + wsel * 1048576;
  int t = threadIdx.x, lane = t & 63, wvi = t >> 6;
  int c = lane & 15, quad = lane >> 4;
  int wm = wvi >> 1, wn = wvi & 1;
  int g0 = mt << 3, gn0 = nt << 3;  // 16-row group bases
  f32x4 acc[4][4] = {};

  for (int kk = 0; kk < 1024; kk += 32) {
    int kb = kk >> 5;
#pragma unroll
    for (int i = 0; i < 2; ++i) {
      int ch = wvi * 2 + i;
      async16(&As[ch << 9], A  + ((g0  + ch) * 32 + kb) * 512 + lane * 8);
      async16(&Bs[ch << 9], Bw + ((gn0 + ch) * 32 + kb) * 512 + lane * 8);
    }
    __syncthreads();                // drains vmcnt for global_load_lds
    bf16x8 af[4], bfr[4];
#pragma unroll
    for (int i = 0; i < 4; ++i) af[i]  = *(const bf16x8*)&As[((wm * 4 + i) << 9) + lane * 8];
#pragma unroll
    for (int j = 0; j < 4; ++j) bfr[j] = *(const bf16x8*)&Bs[((wn * 4 + j) << 9) + lane * 8];
#pragma unroll
    for (int i = 0; i < 4; ++i)
#pragma unroll
      for (int j = 0; j < 4; ++j)
        acc[i][j] = __builtin_amdgcn_mfma_f32_16x16x32_bf16(af[i], bfr[j], acc[i][j], 0, 0, 0);
    __syncthreads();                // protect LDS before next stage
  }

#pragma unroll
  for (int i = 0; i < 4; ++i) {
#pragma unroll
    for (int j = 0; j < 4; ++j) {
      int n = n0 + wn * 64 + j * 16 + c;        // output feature
      int h = n >> 6, d = n & 63;
      int mq = m0 + wm * 64 + i * 16 + quad * 4; // first of the 4 rows (reg dim)
      int bb = mq >> 9, srow = mq & 511;
      if (wsel < 2) {
        // Q_sw / K_sw: [bh][g][dblk][lane=qk*16+(row%16)][jd]; row%16=quad*4+r
        int dblk = d >> 5, qk = (d >> 3) & 3, jd = d & 7;
        int g = srow >> 4;
        short* outp = ws + (wsel == 0 ? OFF_Q : OFF_K);
        size_t base = (size_t)(bb * 16 + h) * 32768 +
                      (size_t)(((g * 2 + dblk) * 64 + qk * 16 + quad * 4)) * 8 + jd;
#pragma unroll
        for (int r = 0; r < 4; ++r) outp[base + r * 8] = f2bf(acc[i][j][r]);
      } else {
        // V_sw: [bh][dg][kblk][lane=qv*16+(d%16)][jv]; keys srow..srow+3
        int dg = d >> 4, cv = d & 15;
        int kblk = srow >> 5, qv = (srow >> 3) & 3, jv = srow & 7;
        s16x4 o;
#pragma unroll
        for (int r = 0; r < 4; ++r) o[r] = f2bf(acc[i][j][r]);
        *(s16x4*)&ws[OFF_VT + (size_t)(bb * 16 + h) * 32768 +
                     (size_t)((dg * 16 + kblk) * 64 + qv * 16 + cv) * 8 + jv] = o;
      }
    }
  }
}

// ---------------------------------------------------------------------------
// Attention v6 (R11): 128-key chunks — half the barrier/drain count.
//   R10 post-mortem: staging is cheap post-swizzle; the per-chunk cost is the
//   2-barrier cadence (vmcnt-drain + s_barrier) paid every 64 keys. Now each
//   iteration stages K+V for 128 keys (32 chunks, 8 async16/wave, 32KB LDS,
//   still 2 blocks/CU) and computes two 64-key halves per barrier pair.
//   Per-half compute, masking, transpose, accumulation identical to R4-R10
//   (verified); only the chunk indexing and loop structure change.
// ---------------------------------------------------------------------------
__global__ __launch_bounds__(256, 2) void attn(short* __restrict__ ws) {
  __shared__ __align__(16) short Kb[8192];   // 16 chunks: [kgrel 0..7][dblk 0..1]
  __shared__ __align__(16) short Vb[8192];   // 16 chunks: [dg 0..3][kbrel 0..3]
  int bi = blockIdx.x;              // 0..511
  int bh = bi >> 2, qcr = bi & 3;
  int qc = (qcr + bh + 2 * (bh >> 6)) & 3;   // rotate so CU pairs mix light/heavy
  int t = threadIdx.x, lane = t & 63, wvi = t >> 6;
  int c = lane & 15, quad = lane >> 4;
  const short* Qsw  = ws + OFF_Q  + (size_t)bh * 32768;
  const short* Ksw  = ws + OFF_K  + (size_t)bh * 32768;
  const short* Vsw  = ws + OFF_VT + (size_t)bh * 32768;
  short* ct = ws + OFF_CT;
  int b = bh >> 4, h = bh & 15;

  int qt0 = qc * 128 + wvi * 32;    // two 16-row subtiles per wave
  int qt1 = qt0 + 16;
  int kn0 = (qt0 + 16 > NP) ? (qt0 + 16) : NP;
  int kn1 = (qt1 + 16 > NP) ? (qt1 + 16) : NP;
  int knb = (qc * 128 + 128 > NP) ? (qc * 128 + 128) : NP;
  int NCH = (knb + 127) >> 7;       // 128-key chunks staged by the block

  // Q^T B-frags from Q_sw (contiguous 1KB wave bursts)
  int qg0 = qt0 >> 4, qg1 = qt1 >> 4;
  bf16x8 q00 = *(const bf16x8*)(Qsw + ((qg0 * 2 + 0) * 64 + lane) * 8);
  bf16x8 q01 = *(const bf16x8*)(Qsw + ((qg0 * 2 + 1) * 64 + lane) * 8);
  bf16x8 q10 = *(const bf16x8*)(Qsw + ((qg1 * 2 + 0) * 64 + lane) * 8);
  bf16x8 q11 = *(const bf16x8*)(Qsw + ((qg1 * 2 + 1) * 64 + lane) * 8);

  f32x4 acc0[4] = {}, acc1[4] = {}; // ctx^T accumulators per subtile
  float l0 = 0.0f, l1 = 0.0f;       // in-lane softmax denominators
  int L0 = c + ((quad & 1) << 5);   // transpose source lane
  bool hilo = quad >= 2;

  for (int chn = 0; chn < NCH; ++chn) {
    int k0 = chn << 7;              // chunk covers keys k0 .. k0+127
    // --- stage 16 K-chunks + 16 V-chunks, 8 async16 per wave ---
    {
      int kg0 = k0 >> 4;            // first 16-key group
      int kblk0 = k0 >> 5;          // first 32-key block
#pragma unroll
      for (int i = 0; i < 4; ++i) {
        int ch = wvi * 4 + i;       // 0..15, wave-uniform
        int kgrel = ch >> 1, f = ch & 1;
        async16(&Kb[ch << 9], Ksw + (((kg0 + kgrel) * 2 + f) * 64 + lane) * 8);
        int dg = ch >> 2, kbrel = ch & 3;
        async16(&Vb[ch << 9], Vsw + ((dg * 16 + kblk0 + kbrel) * 64 + lane) * 8);
      }
    }
    __syncthreads();                // drains vmcnt for global_load_lds

#pragma unroll
    for (int hf = 0; hf < 2; ++hf) {
      int kh = k0 + (hf << 6);      // this 64-key half
      // K A-frags [m=key16][k=d] and V^T A-frags [m=d16][k=key32+..]
      bf16x8 ak[4][2], av[4][2];
#pragma unroll
      for (int mb = 0; mb < 4; ++mb)
#pragma unroll
        for (int f = 0; f < 2; ++f) {
          ak[mb][f] = *(const bf16x8*)&Kb[((((hf * 4 + mb) << 1) + f) << 9) + lane * 8];
          av[mb][f] = *(const bf16x8*)&Vb[(((mb << 2) + (hf << 1) + f) << 9) + lane * 8];
        }

#pragma unroll
      for (int s = 0; s < 2; ++s) {
        int qt = s ? qt1 : qt0;
        int kn = s ? kn1 : kn0;
        if (kh >= kn) continue;     // subtile finished for this half
        bf16x8 bq0 = s ? q10 : q00;
        bf16x8 bq1 = s ? q11 : q01;
        f32x4* acc = s ? acc1 : acc0;

        // --- S^T = K . Q^T : 4 m-blocks of 16 keys ---
        float p[4][4];
#pragma unroll
        for (int mb = 0; mb < 4; ++mb) {
          f32x4 st = {};
          st = __builtin_amdgcn_mfma_f32_16x16x32_bf16(ak[mb][0], bq0, st, 0, 0, 0);
          st = __builtin_amdgcn_mfma_f32_16x16x32_bf16(ak[mb][1], bq1, st, 0, 0, 0);
#pragma unroll
          for (int r = 0; r < 4; ++r) p[mb][r] = __expf(st[r]);
        }

        // --- prefix/causal mask (only halves that can contain invalid keys) ---
        if ((kh + 64 > NP) && (kh + 64 > qt + 1)) {
          int row = qt + c;
#pragma unroll
          for (int mb = 0; mb < 4; ++mb)
#pragma unroll
            for (int r = 0; r < 4; ++r) {
              int key = kh + mb * 16 + (quad << 2) + r;
              bool v = (row < NP) ? (key < NP) : (key <= row);
              p[mb][r] = v ? p[mb][r] : 0.0f;
            }
        }
        float ls = 0.0f;
#pragma unroll
        for (int mb = 0; mb < 4; ++mb)
#pragma unroll
          for (int r = 0; r < 4; ++r) ls += p[mb][r];
        if (s) l1 += ls; else l0 += ls;

        // --- per 32-key half: transpose to B-frag (R3-verified), then PV ---
#pragma unroll
        for (int hh = 0; hh < 2; ++hh) {
          float* pa = p[2 * hh];    // keys kh+32hh+{4quad'+r}
          float* pb = p[2 * hh + 1];
          uint32_t e0 = pack2bf(pa[0], pa[1]);
          uint32_t e1 = pack2bf(pa[2], pa[3]);
          uint32_t e2 = pack2bf(pb[0], pb[1]);
          uint32_t e3 = pack2bf(pb[2], pb[3]);
          uint32_t a0 = (uint32_t)__shfl((int)e0, L0);
          uint32_t b0 = (uint32_t)__shfl((int)e1, L0);
          uint32_t a1 = (uint32_t)__shfl((int)e0, L0 + 16);
          uint32_t b1 = (uint32_t)__shfl((int)e1, L0 + 16);
          uint32_t c0 = (uint32_t)__shfl((int)e2, L0);
          uint32_t d0 = (uint32_t)__shfl((int)e3, L0);
          uint32_t c1 = (uint32_t)__shfl((int)e2, L0 + 16);
          uint32_t d1 = (uint32_t)__shfl((int)e3, L0 + 16);
          union { uint32_t u[4]; bf16x8 v; } bp;
          bp.u[0] = hilo ? c0 : a0;
          bp.u[1] = hilo ? d0 : b0;
          bp.u[2] = hilo ? c1 : a1;
          bp.u[3] = hilo ? d1 : b1;
#pragma unroll
          for (int db = 0; db < 4; ++db)
            acc[db] = __builtin_amdgcn_mfma_f32_16x16x32_bf16(av[db][hh], bp.v, acc[db], 0, 0, 0);
        }
      }
    }
    __syncthreads();                // protect LDS before next stage
  }

  // --- finalize: quad-reduce l, normalize, store ctx SWIZZLED (CT_sw) ---
#pragma unroll
  for (int s = 0; s < 2; ++s) {
    float l = s ? l1 : l0;
    f32x4* acc = s ? acc1 : acc0;
    int qt = s ? qt1 : qt0;
    l += __shfl_xor(l, 16);
    l += __shfl_xor(l, 32);
    float inv = 1.0f / l;
    int g = (b * 512 + qt) >> 4;    // 16-row group (qt multiple of 16)
#pragma unroll
    for (int db = 0; db < 4; ++db) {
      int col0 = h * 64 + db * 16 + quad * 4;   // first of 4 cols (r-run)
      int kb = col0 >> 5, qp = (col0 & 31) >> 3, jo = col0 & 7;
      s16x4 o;
#pragma unroll
      for (int r = 0; r < 4; ++r) o[r] = f2bf(acc[db][r] * inv);
      *(s16x4*)&ct[(size_t)((g * 32 + kb) * 64 + qp * 16 + c) * 8 + jo] = o;
    }
  }
}

// ---------------------------------------------------------------------------
// Output projection (R9 structure, unchanged): 64m x 128n, BK=64, 512 blocks,
// swizzled 1KB-burst staging from CT_sw / WO_sw.
// ---------------------------------------------------------------------------
__global__ __launch_bounds__(256, 2) void gemm_out(const short* __restrict__ ws,
                                                   const float* __restrict__ bias,
                                                   float* __restrict__ out) {
  __shared__ __align__(16) short As[4096];   // 8 chunks
  __shared__ __align__(16) short Bs[8192];   // 16 chunks
  int bx = blockIdx.x;              // 0..511
  int mt = bx >> 3, nt = bx & 7;
  int m0 = mt << 6, n0 = nt << 7;
  const short* A  = ws + OFF_CT;
  const short* Bw = ws + OFF_WO;
  int t = threadIdx.x, lane = t & 63, wvi = t >> 6;
  int c = lane & 15, quad = lane >> 4;
  int wm = wvi >> 1, wn = wvi & 1;   // wave tile 32m x 64n
  int g0 = m0 >> 4, gn0 = n0 >> 4;
  f32x4 acc[2][4] = {};

  for (int kk = 0; kk < 1024; kk += 64) {
    int kb = kk >> 5;
#pragma unroll
    for (int i = 0; i < 6; ++i) {
      int ch = wvi * 6 + i;
      if (ch < 8) {
        int mg = ch >> 1, kh = ch & 1;
        async16(&As[ch << 9], A + ((g0 + mg) * 32 + kb + kh) * 512 + lane * 8);
      } else {
        int cb = ch - 8, mg = cb >> 1, kh = cb & 1;
        async16(&Bs[cb << 9], Bw + ((gn0 + mg) * 32 + kb + kh) * 512 + lane * 8);
      }
    }
    __syncthreads();                // drains vmcnt for global_load_lds

    bf16x8 af[2][2], bfr[4][2];
#pragma unroll
    for (int i = 0; i < 2; ++i)
#pragma unroll
      for (int kh = 0; kh < 2; ++kh)
        af[i][kh] = *(const bf16x8*)&As[((((wm * 2 + i) << 1) + kh) << 9) + lane * 8];
#pragma unroll
    for (int j = 0; j < 4; ++j)
#pragma unroll
      for (int kh = 0; kh < 2; ++kh)
        bfr[j][kh] = *(const bf16x8*)&Bs[((((wn * 4 + j) << 1) + kh) << 9) + lane * 8];
#pragma unroll
    for (int kh = 0; kh < 2; ++kh)
#pragma unroll
      for (int i = 0; i < 2; ++i)
#pragma unroll
        for (int j = 0; j < 4; ++j)
          acc[i][j] = __builtin_amdgcn_mfma_f32_16x16x32_bf16(af[i][kh], bfr[j][kh], acc[i][j], 0, 0, 0);
    __syncthreads();                // protect LDS before next stage
  }

#pragma unroll
  for (int j = 0; j < 4; ++j) {
    int n = n0 + wn * 64 + j * 16 + c;
    float bj = bias[n];
#pragma unroll
    for (int i = 0; i < 2; ++i) {
      int mq = m0 + wm * 32 + i * 16 + quad * 4;
#pragma unroll
      for (int r = 0; r < 4; ++r)
        out[(size_t)(mq + r) * 1024 + n] = acc[i][j][r] + bj;
    }
  }
}

extern "C" void kernel_launch(void* const* d_in, const int* in_sizes, int n_in,
                              void* d_out, int out_size, void* d_ws, size_t ws_size,
                              hipStream_t stream) {
  (void)in_sizes; (void)n_in; (void)out_size; (void)ws_size;  // needs 48 MB of d_ws
  const float* x  = (const float*)d_in[0];
  const float* wq = (const float*)d_in[1];
  const float* wk = (const float*)d_in[2];
  const float* wv = (const float*)d_in[3];
  const float* wo = (const float*)d_in[4];
  const float* bo = (const float*)d_in[5];
  short* ws = (short*)d_ws;
  float* out = (float*)d_out;

  cvt5<<<512, 256, 0, stream>>>(x, wq, wk, wv, wo, ws);
  gemm_qkv<<<768, 256, 0, stream>>>(ws);
  attn<<<512, 256, 0, stream>>>(ws);
  gemm_out<<<512, 256, 0, stream>>>(ws, bo, out);
}